// Round 4
// baseline (240.549 us; speedup 1.0000x reference)
//
#include <hip/hip_runtime.h>
#include <math.h>

#define BB 2
#define LL 2048
#define DD 256
#define PP 32
#define NC 64            // chunks per batch (chunk = 32 rows, 16 odd positions)
#define PI_F 3.14159265358979323846f

// ---------------------------------------------------------------------------
// Kernel 1: encode. 4 token-rows per block, 256 threads, grid B*L/4 = 1024.
// ---------------------------------------------------------------------------
__global__ __launch_bounds__(256) void encode_kernel(
    const float* __restrict__ x, const float* __restrict__ key_W,
    const float* __restrict__ key_b, const float* __restrict__ val_W,
    const float* __restrict__ val_b, float2* __restrict__ ph,
    float* __restrict__ values)
{
    __shared__ float xs[256][8];
    const int tid = threadIdx.x;
    const int row0 = blockIdx.x * 4;

    #pragma unroll
    for (int i = 0; i < 4; ++i)
        xs[tid][i] = x[(row0 + i) * DD + tid];
    __syncthreads();

    if (tid < 128) {   // phases
        const int r = tid >> 5, p = tid & 31;
        float a = key_b[p];
        #pragma unroll 8
        for (int k = 0; k < DD; ++k)
            a += xs[k][r] * key_W[k * PP + p];
        a = tanhf(a) * PI_F;
        float sn, cs;
        sincosf(a, &sn, &cs);
        ph[(row0 + r) * PP + p] = make_float2(cs, sn);
    }

    float acc[4];
    const float bv = val_b[tid];
    #pragma unroll
    for (int i = 0; i < 4; ++i) acc[i] = bv;
    #pragma unroll 8
    for (int k = 0; k < DD; ++k) {
        const float w = val_W[k * DD + tid];
        const float4 a0 = *(const float4*)&xs[k][0];
        acc[0] += a0.x * w; acc[1] += a0.y * w;
        acc[2] += a0.z * w; acc[3] += a0.w * w;
    }
    #pragma unroll
    for (int i = 0; i < 4; ++i)
        values[(row0 + i) * DD + tid] = acc[i];
}

// ---------------------------------------------------------------------------
// Kernel 2: bind. M_c[q][d] = sum_j ph[32c+2j][q] * values[32c+2j+1][d]
// ---------------------------------------------------------------------------
__global__ __launch_bounds__(256) void bind_kernel(
    const float2* __restrict__ ph, const float* __restrict__ values,
    float* __restrict__ M)
{
    __shared__ float phs[16][64];

    const int tid = threadIdx.x;
    const int bid = blockIdx.x;
    const int b  = bid >> 7;
    const int c  = (bid >> 1) & 63;
    const int dh = bid & 1;
    const int base = b * LL;
    const int r0 = 32 * c;

    const float* phf = (const float*)ph;
    #pragma unroll
    for (int k = 0; k < 4; ++k) {
        const int e = tid + k * 256;
        const int j = e >> 6, q = e & 63;
        phs[j][q] = phf[(base + r0 + 2 * j) * 64 + q];
    }
    __syncthreads();

    const int d4 = dh * 128 + (tid & 31) * 4;
    const int qg = tid >> 5;
    float4 acc[8];
    #pragma unroll
    for (int qi = 0; qi < 8; ++qi) acc[qi] = make_float4(0.f,0.f,0.f,0.f);

    #pragma unroll 4
    for (int j = 0; j < 16; ++j) {
        const float4 v = *(const float4*)&values[(base + r0 + 2 * j + 1) * DD + d4];
        #pragma unroll
        for (int qi = 0; qi < 8; ++qi) {
            const float s = phs[j][qg * 8 + qi];
            acc[qi].x += v.x * s; acc[qi].y += v.y * s;
            acc[qi].z += v.z * s; acc[qi].w += v.w * s;
        }
    }

    #pragma unroll
    for (int qi = 0; qi < 8; ++qi) {
        const int q = qg * 8 + qi;
        *(float4*)&M[(((b * NC) + c) * 64 + q) * DD + d4] = acc[qi];
    }
}

// ---------------------------------------------------------------------------
// Kernel 3: prefix. In-place EXCLUSIVE prefix sum over chunk index c.
// ---------------------------------------------------------------------------
__global__ __launch_bounds__(256) void prefix_kernel(float* __restrict__ M)
{
    const int tid = threadIdx.x;
    const int b   = blockIdx.x >> 6;
    const int col = (blockIdx.x & 63) * 256 + tid;
    float run = 0.f;
    #pragma unroll 4
    for (int c = 0; c < NC; ++c) {
        const long a = ((long)(b * NC + c)) * 16384 + col;
        const float tmp = M[a];
        M[a] = run;
        run += tmp;
    }
}

// ---------------------------------------------------------------------------
// Kernel 4: retrieve + LN1 -> rhat (global). 8 l-rows/block, grid 512.
// ---------------------------------------------------------------------------
__device__ inline float red32(float v) {
    v += __shfl_xor(v, 16, 32);
    v += __shfl_xor(v, 8, 32);
    v += __shfl_xor(v, 4, 32);
    v += __shfl_xor(v, 2, 32);
    v += __shfl_xor(v, 1, 32);
    return v;
}

__global__ __launch_bounds__(256) void retrieve_kernel(
    const float2* __restrict__ ph, const float* __restrict__ values,
    const float* __restrict__ Mpre,
    const float* __restrict__ ln1_g, const float* __restrict__ ln1_b,
    float* __restrict__ rhat)
{
    __shared__ float phT[64][10];
    __shared__ float S[16][10];
    __shared__ float ref[8][264];

    const int tid = threadIdx.x;
    const int b   = blockIdx.x >> 8;
    const int lt  = blockIdx.x & 255;
    const int l0  = lt * 8;
    const int base = b * LL;
    const int c     = l0 >> 5;
    const int l0loc = l0 & 31;
    const int jcnt  = l0loc / 2 + 4;

    const float* phf = (const float*)ph;
    #pragma unroll
    for (int k = 0; k < 2; ++k) {
        const int e = tid + k * 256;
        const int r = e >> 6, q = e & 63;
        phT[q][r] = phf[(base + l0 + r) * 64 + q];
    }
    __syncthreads();

    if (tid < 128) {
        const int l = tid & 7, j = tid >> 3;
        const float* ps = &phf[(base + 32 * c + 2 * j) * 64];
        float s = 0.f;
        #pragma unroll 8
        for (int q = 0; q < 64; ++q)
            s += phT[q][l] * ps[q];
        if (2 * j + 1 > l0loc + l) s = 0.f;
        S[j][l] = s;
    }

    const int g = tid >> 6;
    const int d4 = (tid & 63) * 4;
    float4 acc0 = make_float4(0.f,0.f,0.f,0.f);
    float4 acc1 = make_float4(0.f,0.f,0.f,0.f);
    {
        const float* Mc = &Mpre[((long)(b * NC + c)) * 16384 + d4];
        #pragma unroll 8
        for (int q = 0; q < 64; ++q) {
            const float4 m = *(const float4*)&Mc[q * DD];
            const float2 ss = *(const float2*)&phT[q][2 * g];
            acc0.x += m.x * ss.x; acc0.y += m.y * ss.x;
            acc0.z += m.z * ss.x; acc0.w += m.w * ss.x;
            acc1.x += m.x * ss.y; acc1.y += m.y * ss.y;
            acc1.z += m.z * ss.y; acc1.w += m.w * ss.y;
        }
    }
    __syncthreads();

    for (int j = 0; j < jcnt; ++j) {
        const float4 v = *(const float4*)&values[(base + 32 * c + 2 * j + 1) * DD + d4];
        const float2 ss = *(const float2*)&S[j][2 * g];
        acc0.x += v.x * ss.x; acc0.y += v.y * ss.x;
        acc0.z += v.z * ss.x; acc0.w += v.w * ss.x;
        acc1.x += v.x * ss.y; acc1.y += v.y * ss.y;
        acc1.z += v.z * ss.y; acc1.w += v.w * ss.y;
    }

    {
        const float invP = 0.17677669529663687f;
        const int la = l0 + 2 * g;
        int va = (la + 1) / 2; if (va < 1) va = 1;
        const float sc0 = invP * rsqrtf((float)va);
        int vb = (la + 2) / 2; if (vb < 1) vb = 1;
        const float sc1 = invP * rsqrtf((float)vb);
        *(float4*)&ref[2 * g][d4] = make_float4(acc0.x*sc0, acc0.y*sc0, acc0.z*sc0, acc0.w*sc0);
        *(float4*)&ref[2 * g + 1][d4] = make_float4(acc1.x*sc1, acc1.y*sc1, acc1.z*sc1, acc1.w*sc1);
    }
    __syncthreads();

    // LN1 -> rhat
    {
        const long row0 = (long)blockIdx.x * 8;
        const int r = tid >> 5, lane = tid & 31;
        float v[8], s = 0.f, sq = 0.f;
        #pragma unroll
        for (int i = 0; i < 8; ++i) {
            v[i] = ref[r][lane + 32 * i];
            s += v[i]; sq += v[i] * v[i];
        }
        s = red32(s); sq = red32(sq);
        const float m = s * (1.f / 256.f);
        const float inv = rsqrtf(sq * (1.f / 256.f) - m * m + 1e-5f);
        #pragma unroll
        for (int i = 0; i < 8; ++i) {
            const int cc = lane + 32 * i;
            rhat[(row0 + r) * DD + cc] = (v[i] - m) * inv * ln1_g[cc] + ln1_b[cc];
        }
    }
}

// ---------------------------------------------------------------------------
// Kernel 5: G1. h = gelu(rhat @ W1 + b1).  [4096x256]@[256x512]
// Tile M=32, N=128; grid 128x4=512. Thread: rows rg*8..+7, cols (tid&63)*2.
// ---------------------------------------------------------------------------
__global__ __launch_bounds__(256) void gemm1_kernel(
    const float* __restrict__ rhat, const float* __restrict__ W1,
    const float* __restrict__ b1, float* __restrict__ h)
{
    __shared__ float aT[32][36];
    const int tid = threadIdx.x;
    const int nt = blockIdx.x >> 7;
    const int mt = blockIdx.x & 127;
    const int r0 = mt * 32;
    const int cc = nt * 128 + (tid & 63) * 2;
    const int rg = tid >> 6;

    float acc0[8], acc1[8];
    #pragma unroll
    for (int i = 0; i < 8; ++i) { acc0[i] = 0.f; acc1[i] = 0.f; }

    const int lrow = tid >> 3;
    const int lk4  = (tid & 7) * 4;

    for (int k0 = 0; k0 < 256; k0 += 32) {
        __syncthreads();
        const float4 av = *(const float4*)&rhat[(r0 + lrow) * DD + k0 + lk4];
        aT[lk4 + 0][lrow] = av.x; aT[lk4 + 1][lrow] = av.y;
        aT[lk4 + 2][lrow] = av.z; aT[lk4 + 3][lrow] = av.w;
        __syncthreads();
        #pragma unroll
        for (int k = 0; k < 32; ++k) {
            const float2 w = *(const float2*)&W1[(k0 + k) * 512 + cc];
            const float4 a0 = *(const float4*)&aT[k][rg * 8];
            const float4 a1 = *(const float4*)&aT[k][rg * 8 + 4];
            acc0[0] += a0.x * w.x; acc1[0] += a0.x * w.y;
            acc0[1] += a0.y * w.x; acc1[1] += a0.y * w.y;
            acc0[2] += a0.z * w.x; acc1[2] += a0.z * w.y;
            acc0[3] += a0.w * w.x; acc1[3] += a0.w * w.y;
            acc0[4] += a1.x * w.x; acc1[4] += a1.x * w.y;
            acc0[5] += a1.y * w.x; acc1[5] += a1.y * w.y;
            acc0[6] += a1.z * w.x; acc1[6] += a1.z * w.y;
            acc0[7] += a1.w * w.x; acc1[7] += a1.w * w.y;
        }
    }

    const float bb0 = b1[cc], bb1 = b1[cc + 1];
    #pragma unroll
    for (int i = 0; i < 8; ++i) {
        float v0 = acc0[i] + bb0;
        float v1 = acc1[i] + bb1;
        v0 = 0.5f * v0 * (1.f + erff(v0 * 0.70710678118654752f));
        v1 = 0.5f * v1 * (1.f + erff(v1 * 0.70710678118654752f));
        *(float2*)&h[(r0 + rg * 8 + i) * 512 + cc] = make_float2(v0, v1);
    }
}

// ---------------------------------------------------------------------------
// Kernel 6: G2. refined = h @ W2 + b2.  [4096x512]@[512x256]
// Tile M=16, N=128; grid 256x2=512. Thread: rows rg*4..+3, cols (tid&63)*2.
// ---------------------------------------------------------------------------
__global__ __launch_bounds__(256) void gemm2_kernel(
    const float* __restrict__ h, const float* __restrict__ W2,
    const float* __restrict__ b2, float* __restrict__ refined)
{
    __shared__ float aT[32][20];
    const int tid = threadIdx.x;
    const int nt = blockIdx.x >> 8;
    const int mt = blockIdx.x & 255;
    const int r0 = mt * 16;
    const int cc = nt * 128 + (tid & 63) * 2;
    const int rg = tid >> 6;

    float acc0[4], acc1[4];
    #pragma unroll
    for (int i = 0; i < 4; ++i) { acc0[i] = 0.f; acc1[i] = 0.f; }

    const int lrow = tid >> 4;
    const int lk2  = (tid & 15) * 2;

    for (int k0 = 0; k0 < 512; k0 += 32) {
        __syncthreads();
        const float2 av = *(const float2*)&h[(r0 + lrow) * 512 + k0 + lk2];
        aT[lk2 + 0][lrow] = av.x; aT[lk2 + 1][lrow] = av.y;
        __syncthreads();
        #pragma unroll
        for (int k = 0; k < 32; ++k) {
            const float2 w = *(const float2*)&W2[(k0 + k) * DD + cc];
            const float4 a = *(const float4*)&aT[k][rg * 4];
            acc0[0] += a.x * w.x; acc1[0] += a.x * w.y;
            acc0[1] += a.y * w.x; acc1[1] += a.y * w.y;
            acc0[2] += a.z * w.x; acc1[2] += a.z * w.y;
            acc0[3] += a.w * w.x; acc1[3] += a.w * w.y;
        }
    }

    const float bb0 = b2[cc], bb1 = b2[cc + 1];
    #pragma unroll
    for (int i = 0; i < 4; ++i)
        *(float2*)&refined[(r0 + rg * 4 + i) * DD + cc] =
            make_float2(acc0[i] + bb0, acc1[i] + bb1);
}

// ---------------------------------------------------------------------------
// Kernel 7: LN2. refined -> shat. 8 rows/block, grid 512.
// ---------------------------------------------------------------------------
__global__ __launch_bounds__(256) void ln2_kernel(
    const float* __restrict__ refined, const float* __restrict__ ln2_g,
    const float* __restrict__ ln2_b, float* __restrict__ shat)
{
    const int tid = threadIdx.x;
    const long row = (long)blockIdx.x * 8 + (tid >> 5);
    const int lane = tid & 31;
    float v[8], s = 0.f, sq = 0.f;
    #pragma unroll
    for (int i = 0; i < 8; ++i) {
        v[i] = refined[row * DD + lane + 32 * i];
        s += v[i]; sq += v[i] * v[i];
    }
    s = red32(s); sq = red32(sq);
    const float m = s * (1.f / 256.f);
    const float inv = rsqrtf(sq * (1.f / 256.f) - m * m + 1e-5f);
    #pragma unroll
    for (int i = 0; i < 8; ++i) {
        const int cc = lane + 32 * i;
        shat[row * DD + cc] = (v[i] - m) * inv * ln2_g[cc] + ln2_b[cc];
    }
}

// ---------------------------------------------------------------------------
// Kernel 8: G3. out = x + shat @ Wo + bo.  [4096x256]@[256x256]
// Tile M=16, N=128; grid 256x2=512.
// ---------------------------------------------------------------------------
__global__ __launch_bounds__(256) void gemm3_kernel(
    const float* __restrict__ shat, const float* __restrict__ Wo,
    const float* __restrict__ bo, const float* __restrict__ x,
    float* __restrict__ out)
{
    __shared__ float aT[32][20];
    const int tid = threadIdx.x;
    const int nt = blockIdx.x >> 8;
    const int mt = blockIdx.x & 255;
    const int r0 = mt * 16;
    const int cc = nt * 128 + (tid & 63) * 2;
    const int rg = tid >> 6;

    float acc0[4], acc1[4];
    #pragma unroll
    for (int i = 0; i < 4; ++i) { acc0[i] = 0.f; acc1[i] = 0.f; }

    const int lrow = tid >> 4;
    const int lk2  = (tid & 15) * 2;

    for (int k0 = 0; k0 < 256; k0 += 32) {
        __syncthreads();
        const float2 av = *(const float2*)&shat[(r0 + lrow) * DD + k0 + lk2];
        aT[lk2 + 0][lrow] = av.x; aT[lk2 + 1][lrow] = av.y;
        __syncthreads();
        #pragma unroll
        for (int k = 0; k < 32; ++k) {
            const float2 w = *(const float2*)&Wo[(k0 + k) * DD + cc];
            const float4 a = *(const float4*)&aT[k][rg * 4];
            acc0[0] += a.x * w.x; acc1[0] += a.x * w.y;
            acc0[1] += a.y * w.x; acc1[1] += a.y * w.y;
            acc0[2] += a.z * w.x; acc1[2] += a.z * w.y;
            acc0[3] += a.w * w.x; acc1[3] += a.w * w.y;
        }
    }

    const float bb0 = bo[cc], bb1 = bo[cc + 1];
    #pragma unroll
    for (int i = 0; i < 4; ++i) {
        const long rw = (long)(r0 + rg * 4 + i) * DD + cc;
        const float2 xv = *(const float2*)&x[rw];
        *(float2*)&out[rw] = make_float2(xv.x + acc0[i] + bb0, xv.y + acc1[i] + bb1);
    }
}

// ---------------------------------------------------------------------------
extern "C" void kernel_launch(void* const* d_in, const int* in_sizes, int n_in,
                              void* d_out, int out_size, void* d_ws, size_t ws_size,
                              hipStream_t stream)
{
    const float* x     = (const float*)d_in[0];
    const float* key_W = (const float*)d_in[1];
    const float* key_b = (const float*)d_in[2];
    const float* val_W = (const float*)d_in[3];
    const float* val_b = (const float*)d_in[4];
    const float* ln1_g = (const float*)d_in[5];
    const float* ln1_b = (const float*)d_in[6];
    const float* W1    = (const float*)d_in[7];
    const float* b1    = (const float*)d_in[8];
    const float* W2    = (const float*)d_in[9];
    const float* b2    = (const float*)d_in[10];
    const float* ln2_g = (const float*)d_in[11];
    const float* ln2_b = (const float*)d_in[12];
    const float* Wo    = (const float*)d_in[13];
    const float* bo    = (const float*)d_in[14];
    float* outp = (float*)d_out;

    float* ws = (float*)d_ws;
    float2* ph    = (float2*)ws;                    // 262144 floats
    float* values = ws + 262144;                    // 1048576 (reused: refined)
    float* M      = values + 1048576;               // 2097152 (reused: h)
    float* rhat   = M + 2097152;                    // 1048576 (reused: shat)
    float* h       = M;        // M (Mpre) dead after retrieve_kernel
    float* refined = values;   // values dead after retrieve_kernel
    float* shat    = rhat;     // rhat dead after gemm1

    encode_kernel<<<BB * LL / 4, 256, 0, stream>>>(x, key_W, key_b, val_W, val_b,
                                                   ph, values);
    bind_kernel<<<BB * NC * 2, 256, 0, stream>>>(ph, values, M);
    prefix_kernel<<<BB * 64, 256, 0, stream>>>(M);
    retrieve_kernel<<<BB * (LL / 8), 256, 0, stream>>>(ph, values, M,
                                                       ln1_g, ln1_b, rhat);
    gemm1_kernel<<<512, 256, 0, stream>>>(rhat, W1, b1, h);
    gemm2_kernel<<<512, 256, 0, stream>>>(h, W2, b2, refined);
    ln2_kernel<<<BB * LL / 8, 256, 0, stream>>>(refined, ln2_g, ln2_b, shat);
    gemm3_kernel<<<512, 256, 0, stream>>>(shat, Wo, bo, x, outp);
}

// Round 5
// 159.275 us; speedup vs baseline: 1.5103x; 1.5103x over previous
//
#include <hip/hip_runtime.h>
#include <math.h>

#define BB 2
#define LL 2048
#define DD 256
#define PP 32
#define NC 64
#define PI_F 3.14159265358979323846f

typedef __attribute__((ext_vector_type(8))) short bf16x8;
typedef __attribute__((ext_vector_type(4))) float f32x4;
typedef unsigned short ushort_t;
typedef unsigned int uint_t;

__device__ inline ushort_t f2bf(float x) {
    uint_t u = __float_as_uint(x);
    uint_t r = (u + 0x7fffu + ((u >> 16) & 1u)) >> 16;
    return (ushort_t)r;
}

// ---------------------------------------------------------------------------
// Kernel 0: convert + transpose weights to bf16 [N][K].
// blocks 0-31: W1 (K=256,N=512); 32-63: W2 (K=512,N=256); 64-79: Wo (256,256)
// ---------------------------------------------------------------------------
__global__ __launch_bounds__(256) void convw_kernel(
    const float* __restrict__ W1, const float* __restrict__ W2,
    const float* __restrict__ Wo, ushort_t* __restrict__ W1t,
    ushort_t* __restrict__ W2t, ushort_t* __restrict__ Wot)
{
    __shared__ float T[64][65];
    const int bid = blockIdx.x;
    const float* W; ushort_t* Wt; int K, N, tile;
    if (bid < 32)      { W = W1; Wt = W1t; K = 256; N = 512; tile = bid; }
    else if (bid < 64) { W = W2; Wt = W2t; K = 512; N = 256; tile = bid - 32; }
    else               { W = Wo; Wt = Wot; K = 256; N = 256; tile = bid - 64; }
    const int ntiles = N / 64;
    const int k0 = (tile / ntiles) * 64, n0 = (tile % ntiles) * 64;
    const int t = threadIdx.x;
    {
        const int rr = t >> 2, cb = (t & 3) * 16;
        #pragma unroll
        for (int i = 0; i < 16; i += 4) {
            const float4 v = *(const float4*)&W[(k0 + rr) * N + n0 + cb + i];
            T[rr][cb + i + 0] = v.x; T[rr][cb + i + 1] = v.y;
            T[rr][cb + i + 2] = v.z; T[rr][cb + i + 3] = v.w;
        }
    }
    __syncthreads();
    {
        const int n = t >> 2, kb = (t & 3) * 16;
        #pragma unroll
        for (int i = 0; i < 16; ++i)
            Wt[(n0 + n) * K + k0 + kb + i] = f2bf(T[kb + i][n]);
    }
}

// ---------------------------------------------------------------------------
// Kernel 1: encode. 4 token-rows per block, grid B*L/4 = 1024.
// ---------------------------------------------------------------------------
__global__ __launch_bounds__(256) void encode_kernel(
    const float* __restrict__ x, const float* __restrict__ key_W,
    const float* __restrict__ key_b, const float* __restrict__ val_W,
    const float* __restrict__ val_b, float2* __restrict__ ph,
    float* __restrict__ values)
{
    __shared__ float xs[256][8];
    const int tid = threadIdx.x;
    const int row0 = blockIdx.x * 4;

    #pragma unroll
    for (int i = 0; i < 4; ++i)
        xs[tid][i] = x[(row0 + i) * DD + tid];
    __syncthreads();

    if (tid < 128) {
        const int r = tid >> 5, p = tid & 31;
        float a = key_b[p];
        #pragma unroll 8
        for (int k = 0; k < DD; ++k)
            a += xs[k][r] * key_W[k * PP + p];
        a = tanhf(a) * PI_F;
        float sn, cs;
        sincosf(a, &sn, &cs);
        ph[(row0 + r) * PP + p] = make_float2(cs, sn);
    }

    float acc[4];
    const float bv = val_b[tid];
    #pragma unroll
    for (int i = 0; i < 4; ++i) acc[i] = bv;
    #pragma unroll 8
    for (int k = 0; k < DD; ++k) {
        const float w = val_W[k * DD + tid];
        const float4 a0 = *(const float4*)&xs[k][0];
        acc[0] += a0.x * w; acc[1] += a0.y * w;
        acc[2] += a0.z * w; acc[3] += a0.w * w;
    }
    #pragma unroll
    for (int i = 0; i < 4; ++i)
        values[(row0 + i) * DD + tid] = acc[i];
}

// ---------------------------------------------------------------------------
// Kernel 2: bind. M_c[q][d] = sum_j ph[32c+2j][q] * values[32c+2j+1][d]
// ---------------------------------------------------------------------------
__global__ __launch_bounds__(256) void bind_kernel(
    const float2* __restrict__ ph, const float* __restrict__ values,
    float* __restrict__ M)
{
    __shared__ float phs[16][64];
    const int tid = threadIdx.x;
    const int bid = blockIdx.x;
    const int b  = bid >> 7;
    const int c  = (bid >> 1) & 63;
    const int dh = bid & 1;
    const int base = b * LL;
    const int r0 = 32 * c;

    const float* phf = (const float*)ph;
    #pragma unroll
    for (int k = 0; k < 4; ++k) {
        const int e = tid + k * 256;
        const int j = e >> 6, q = e & 63;
        phs[j][q] = phf[(base + r0 + 2 * j) * 64 + q];
    }
    __syncthreads();

    const int d4 = dh * 128 + (tid & 31) * 4;
    const int qg = tid >> 5;
    float4 acc[8];
    #pragma unroll
    for (int qi = 0; qi < 8; ++qi) acc[qi] = make_float4(0.f,0.f,0.f,0.f);

    #pragma unroll 4
    for (int j = 0; j < 16; ++j) {
        const float4 v = *(const float4*)&values[(base + r0 + 2 * j + 1) * DD + d4];
        #pragma unroll
        for (int qi = 0; qi < 8; ++qi) {
            const float s = phs[j][qg * 8 + qi];
            acc[qi].x += v.x * s; acc[qi].y += v.y * s;
            acc[qi].z += v.z * s; acc[qi].w += v.w * s;
        }
    }
    #pragma unroll
    for (int qi = 0; qi < 8; ++qi) {
        const int q = qg * 8 + qi;
        *(float4*)&M[(((b * NC) + c) * 64 + q) * DD + d4] = acc[qi];
    }
}

// ---------------------------------------------------------------------------
// Kernel 3: prefix. In-place EXCLUSIVE prefix sum over chunk index c.
// ---------------------------------------------------------------------------
__global__ __launch_bounds__(256) void prefix_kernel(float* __restrict__ M)
{
    const int tid = threadIdx.x;
    const int b   = blockIdx.x >> 6;
    const int col = (blockIdx.x & 63) * 256 + tid;
    float run = 0.f;
    #pragma unroll 4
    for (int c = 0; c < NC; ++c) {
        const long a = ((long)(b * NC + c)) * 16384 + col;
        const float tmp = M[a];
        M[a] = run;
        run += tmp;
    }
}

// ---------------------------------------------------------------------------
// Kernel 4: retrieve + LN1 -> rhat (bf16). 8 l-rows/block, grid 512.
// ---------------------------------------------------------------------------
__device__ inline float red32(float v) {
    v += __shfl_xor(v, 16, 32);
    v += __shfl_xor(v, 8, 32);
    v += __shfl_xor(v, 4, 32);
    v += __shfl_xor(v, 2, 32);
    v += __shfl_xor(v, 1, 32);
    return v;
}

__global__ __launch_bounds__(256) void retrieve_kernel(
    const float2* __restrict__ ph, const float* __restrict__ values,
    const float* __restrict__ Mpre,
    const float* __restrict__ ln1_g, const float* __restrict__ ln1_b,
    ushort_t* __restrict__ rhat)
{
    __shared__ float phT[64][10];
    __shared__ float S[16][10];
    __shared__ float ref[8][264];

    const int tid = threadIdx.x;
    const int b   = blockIdx.x >> 8;
    const int lt  = blockIdx.x & 255;
    const int l0  = lt * 8;
    const int base = b * LL;
    const int c     = l0 >> 5;
    const int l0loc = l0 & 31;
    const int jcnt  = l0loc / 2 + 4;

    const float* phf = (const float*)ph;
    #pragma unroll
    for (int k = 0; k < 2; ++k) {
        const int e = tid + k * 256;
        const int r = e >> 6, q = e & 63;
        phT[q][r] = phf[(base + l0 + r) * 64 + q];
    }
    __syncthreads();

    if (tid < 128) {
        const int l = tid & 7, j = tid >> 3;
        const float* ps = &phf[(base + 32 * c + 2 * j) * 64];
        float s = 0.f;
        #pragma unroll 8
        for (int q = 0; q < 64; ++q)
            s += phT[q][l] * ps[q];
        if (2 * j + 1 > l0loc + l) s = 0.f;
        S[j][l] = s;
    }

    const int g = tid >> 6;
    const int d4 = (tid & 63) * 4;
    float4 acc0 = make_float4(0.f,0.f,0.f,0.f);
    float4 acc1 = make_float4(0.f,0.f,0.f,0.f);
    {
        const float* Mc = &Mpre[((long)(b * NC + c)) * 16384 + d4];
        #pragma unroll 8
        for (int q = 0; q < 64; ++q) {
            const float4 m = *(const float4*)&Mc[q * DD];
            const float2 ss = *(const float2*)&phT[q][2 * g];
            acc0.x += m.x * ss.x; acc0.y += m.y * ss.x;
            acc0.z += m.z * ss.x; acc0.w += m.w * ss.x;
            acc1.x += m.x * ss.y; acc1.y += m.y * ss.y;
            acc1.z += m.z * ss.y; acc1.w += m.w * ss.y;
        }
    }
    __syncthreads();

    for (int j = 0; j < jcnt; ++j) {
        const float4 v = *(const float4*)&values[(base + 32 * c + 2 * j + 1) * DD + d4];
        const float2 ss = *(const float2*)&S[j][2 * g];
        acc0.x += v.x * ss.x; acc0.y += v.y * ss.x;
        acc0.z += v.z * ss.x; acc0.w += v.w * ss.x;
        acc1.x += v.x * ss.y; acc1.y += v.y * ss.y;
        acc1.z += v.z * ss.y; acc1.w += v.w * ss.y;
    }

    {
        const float invP = 0.17677669529663687f;
        const int la = l0 + 2 * g;
        int va = (la + 1) / 2; if (va < 1) va = 1;
        const float sc0 = invP * rsqrtf((float)va);
        int vb = (la + 2) / 2; if (vb < 1) vb = 1;
        const float sc1 = invP * rsqrtf((float)vb);
        *(float4*)&ref[2 * g][d4] = make_float4(acc0.x*sc0, acc0.y*sc0, acc0.z*sc0, acc0.w*sc0);
        *(float4*)&ref[2 * g + 1][d4] = make_float4(acc1.x*sc1, acc1.y*sc1, acc1.z*sc1, acc1.w*sc1);
    }
    __syncthreads();

    {
        const long row0 = (long)blockIdx.x * 8;
        const int r = tid >> 5, lane = tid & 31;
        float v[8], s = 0.f, sq = 0.f;
        #pragma unroll
        for (int i = 0; i < 8; ++i) {
            v[i] = ref[r][lane + 32 * i];
            s += v[i]; sq += v[i] * v[i];
        }
        s = red32(s); sq = red32(sq);
        const float m = s * (1.f / 256.f);
        const float inv = rsqrtf(sq * (1.f / 256.f) - m * m + 1e-5f);
        #pragma unroll
        for (int i = 0; i < 8; ++i) {
            const int cc = lane + 32 * i;
            rhat[(row0 + r) * DD + cc] = f2bf((v[i] - m) * inv * ln1_g[cc] + ln1_b[cc]);
        }
    }
}

// ---------------------------------------------------------------------------
// MFMA GEMM: C[M=4096][N] = A[M][K](bf16) @ Bt[N][K](bf16)^T + bias, epilogue.
// BM=16, BN=64, 256 threads = 4 waves; wave wv owns cols wv*16..+15.
// MODE 0: gelu -> bf16 out; MODE 1: bias -> f32; MODE 2: bias+resid -> f32.
// ---------------------------------------------------------------------------
template<int K, int N, int MODE>
__global__ __launch_bounds__(256) void mfma_gemm(
    const ushort_t* __restrict__ A, const ushort_t* __restrict__ Bt,
    const float* __restrict__ bias, const float* __restrict__ resid,
    void* __restrict__ out)
{
    __shared__ ushort_t As[16][136];
    __shared__ ushort_t Bs[64][136];
    const int tid = threadIdx.x;
    const int mt = blockIdx.x & 255;          // 4096/16 = 256 m-tiles
    const int nt = blockIdx.x >> 8;
    const int m0 = mt * 16, n0 = nt * 64;
    const int wv = tid >> 6, lane = tid & 63;
    const int qd = lane >> 4, mc = lane & 15;

    f32x4 acc = {0.f, 0.f, 0.f, 0.f};

    const int ar = tid >> 4, ak = (tid & 15) * 8;
    const int bn = tid >> 2, bk = (tid & 3) * 32;

    for (int k0 = 0; k0 < K; k0 += 128) {
        __syncthreads();
        *(uint4*)&As[ar][ak] = *(const uint4*)&A[(long)(m0 + ar) * K + k0 + ak];
        {
            const ushort_t* src = &Bt[(long)(n0 + bn) * K + k0 + bk];
            *(uint4*)&Bs[bn][bk +  0] = *(const uint4*)&src[0];
            *(uint4*)&Bs[bn][bk +  8] = *(const uint4*)&src[8];
            *(uint4*)&Bs[bn][bk + 16] = *(const uint4*)&src[16];
            *(uint4*)&Bs[bn][bk + 24] = *(const uint4*)&src[24];
        }
        __syncthreads();
        #pragma unroll
        for (int ko = 0; ko < 128; ko += 32) {
            const bf16x8 a = *(const bf16x8*)&As[mc][ko + qd * 8];
            const bf16x8 b = *(const bf16x8*)&Bs[wv * 16 + mc][ko + qd * 8];
            acc = __builtin_amdgcn_mfma_f32_16x16x32_bf16(a, b, acc, 0, 0, 0);
        }
    }

    const int nn = n0 + wv * 16 + mc;
    const float bb = bias[nn];
    #pragma unroll
    for (int r = 0; r < 4; ++r) {
        const long row = m0 + qd * 4 + r;
        float v = acc[r] + bb;
        if (MODE == 0) {
            v = 0.5f * v * (1.f + erff(v * 0.70710678118654752f));
            ((ushort_t*)out)[row * N + nn] = f2bf(v);
        } else if (MODE == 1) {
            ((float*)out)[row * N + nn] = v;
        } else {
            ((float*)out)[row * N + nn] = v + resid[row * N + nn];
        }
    }
}

// ---------------------------------------------------------------------------
// LN2: refined (f32) -> shat (bf16). 8 rows/block, grid 512.
// ---------------------------------------------------------------------------
__global__ __launch_bounds__(256) void ln2_kernel(
    const float* __restrict__ refined, const float* __restrict__ ln2_g,
    const float* __restrict__ ln2_b, ushort_t* __restrict__ shat)
{
    const int tid = threadIdx.x;
    const long row = (long)blockIdx.x * 8 + (tid >> 5);
    const int lane = tid & 31;
    float v[8], s = 0.f, sq = 0.f;
    #pragma unroll
    for (int i = 0; i < 8; ++i) {
        v[i] = refined[row * DD + lane + 32 * i];
        s += v[i]; sq += v[i] * v[i];
    }
    s = red32(s); sq = red32(sq);
    const float m = s * (1.f / 256.f);
    const float inv = rsqrtf(sq * (1.f / 256.f) - m * m + 1e-5f);
    #pragma unroll
    for (int i = 0; i < 8; ++i) {
        const int cc = lane + 32 * i;
        shat[row * DD + cc] = f2bf((v[i] - m) * inv * ln2_g[cc] + ln2_b[cc]);
    }
}

// ---------------------------------------------------------------------------
extern "C" void kernel_launch(void* const* d_in, const int* in_sizes, int n_in,
                              void* d_out, int out_size, void* d_ws, size_t ws_size,
                              hipStream_t stream)
{
    const float* x     = (const float*)d_in[0];
    const float* key_W = (const float*)d_in[1];
    const float* key_b = (const float*)d_in[2];
    const float* val_W = (const float*)d_in[3];
    const float* val_b = (const float*)d_in[4];
    const float* ln1_g = (const float*)d_in[5];
    const float* ln1_b = (const float*)d_in[6];
    const float* W1    = (const float*)d_in[7];
    const float* b1    = (const float*)d_in[8];
    const float* W2    = (const float*)d_in[9];
    const float* b2    = (const float*)d_in[10];
    const float* ln2_g = (const float*)d_in[11];
    const float* ln2_b = (const float*)d_in[12];
    const float* Wo    = (const float*)d_in[13];
    const float* bo    = (const float*)d_in[14];
    float* outp = (float*)d_out;

    float* ws = (float*)d_ws;
    float2* ph       = (float2*)ws;                       // 262144 f32
    float*  values   = ws + 262144;                       // 1048576 f32 (-> refined)
    float*  M        = values + 1048576;                  // 2097152 f32 (-> h_bf, shat_bf)
    ushort_t* rhat_b = (ushort_t*)(M + 2097152);          // 1048576 us (524288 f32)
    ushort_t* W1t    = (ushort_t*)(M + 2097152 + 524288); // 131072 us (65536 f32)
    ushort_t* W2t    = W1t + 131072;                      // 131072 us
    ushort_t* Wot    = W2t + 131072;                      // 65536 us
    // reuse after retrieve:
    ushort_t* h_b    = (ushort_t*)M;                      // 2097152 us (4 MB)
    ushort_t* shat_b = (ushort_t*)(M + 1048576);          // 1048576 us (2 MB)
    float* refined   = values;
    // total ws: ~16.4 MB (within prior footprint)

    convw_kernel<<<80, 256, 0, stream>>>(W1, W2, Wo, W1t, W2t, Wot);
    encode_kernel<<<BB * LL / 4, 256, 0, stream>>>(x, key_W, key_b, val_W, val_b,
                                                   ph, values);
    bind_kernel<<<BB * NC * 2, 256, 0, stream>>>(ph, values, M);
    prefix_kernel<<<BB * 64, 256, 0, stream>>>(M);
    retrieve_kernel<<<BB * (LL / 8), 256, 0, stream>>>(ph, values, M,
                                                       ln1_g, ln1_b, rhat_b);
    mfma_gemm<256, 512, 0><<<256 * 8, 256, 0, stream>>>(rhat_b, W1t, b1, nullptr, h_b);
    mfma_gemm<512, 256, 1><<<256 * 4, 256, 0, stream>>>(h_b, W2t, b2, nullptr, refined);
    ln2_kernel<<<BB * LL / 8, 256, 0, stream>>>(refined, ln2_g, ln2_b, shat_b);
    mfma_gemm<256, 256, 2><<<256 * 4, 256, 0, stream>>>(shat_b, Wot, bo, x, outp);
}

// Round 6
// 155.954 us; speedup vs baseline: 1.5424x; 1.0213x over previous
//
#include <hip/hip_runtime.h>
#include <math.h>

#define BB 2
#define LL 2048
#define DD 256
#define PP 32
#define NC 64
#define PI_F 3.14159265358979323846f

typedef __attribute__((ext_vector_type(8))) short bf16x8;
typedef __attribute__((ext_vector_type(4))) float f32x4;
typedef unsigned short ushort_t;
typedef unsigned int uint_t;

__device__ inline ushort_t f2bf(float x) {
    uint_t u = __float_as_uint(x);
    uint_t r = (u + 0x7fffu + ((u >> 16) & 1u)) >> 16;
    return (ushort_t)r;
}

// ---------------------------------------------------------------------------
// Kernel 0: prep. blocks 0-31: W1^T; 32-63: W2^T; 64-79: Wo^T; 80-95: val_W^T
// (all bf16 [N][K]); blocks 96-127: x -> bf16 (row-major copy).
// ---------------------------------------------------------------------------
__global__ __launch_bounds__(256) void prep_kernel(
    const float* __restrict__ W1, const float* __restrict__ W2,
    const float* __restrict__ Wo, const float* __restrict__ valW,
    const float* __restrict__ x,
    ushort_t* __restrict__ W1t, ushort_t* __restrict__ W2t,
    ushort_t* __restrict__ Wot, ushort_t* __restrict__ valWt,
    ushort_t* __restrict__ xb)
{
    const int bid = blockIdx.x;
    const int t = threadIdx.x;
    if (bid < 96) {
        __shared__ float T[64][65];
        const float* W; ushort_t* Wt; int K, N, tile;
        if (bid < 32)      { W = W1;   Wt = W1t;   K = 256; N = 512; tile = bid; }
        else if (bid < 64) { W = W2;   Wt = W2t;   K = 512; N = 256; tile = bid - 32; }
        else if (bid < 80) { W = Wo;   Wt = Wot;   K = 256; N = 256; tile = bid - 64; }
        else               { W = valW; Wt = valWt; K = 256; N = 256; tile = bid - 80; }
        const int ntiles = N / 64;
        const int k0 = (tile / ntiles) * 64, n0 = (tile % ntiles) * 64;
        {
            const int rr = t >> 2, cb = (t & 3) * 16;
            #pragma unroll
            for (int i = 0; i < 16; i += 4) {
                const float4 v = *(const float4*)&W[(k0 + rr) * N + n0 + cb + i];
                T[rr][cb + i + 0] = v.x; T[rr][cb + i + 1] = v.y;
                T[rr][cb + i + 2] = v.z; T[rr][cb + i + 3] = v.w;
            }
        }
        __syncthreads();
        {
            const int n = t >> 2, kb = (t & 3) * 16;
            #pragma unroll
            for (int i = 0; i < 16; ++i)
                Wt[(n0 + n) * K + k0 + kb + i] = f2bf(T[kb + i][n]);
        }
    } else {
        const long base = (long)(bid - 96) * 32768;
        #pragma unroll 4
        for (int i = 0; i < 16; ++i) {
            const long e = base + i * 2048 + t * 8;
            const float4 v0 = *(const float4*)&x[e];
            const float4 v1 = *(const float4*)&x[e + 4];
            ushort_t o[8];
            o[0] = f2bf(v0.x); o[1] = f2bf(v0.y); o[2] = f2bf(v0.z); o[3] = f2bf(v0.w);
            o[4] = f2bf(v1.x); o[5] = f2bf(v1.y); o[6] = f2bf(v1.z); o[7] = f2bf(v1.w);
            *(uint4*)&xb[e] = *(uint4*)o;
        }
    }
}

// ---------------------------------------------------------------------------
// Kernel 1: encode_key. phases (fp32 exact) -> ph. 8 rows/block, grid 512.
// ---------------------------------------------------------------------------
__global__ __launch_bounds__(256) void encode_key_kernel(
    const float* __restrict__ x, const float* __restrict__ key_W,
    const float* __restrict__ key_b, float2* __restrict__ ph)
{
    __shared__ float xs[256][8];
    const int tid = threadIdx.x;
    const int row0 = blockIdx.x * 8;

    #pragma unroll
    for (int i = 0; i < 8; ++i)
        xs[tid][i] = x[(row0 + i) * DD + tid];
    __syncthreads();

    const int r = tid >> 5, p = tid & 31;
    float a = key_b[p];
    #pragma unroll 8
    for (int k = 0; k < DD; ++k)
        a += xs[k][r] * key_W[k * PP + p];
    a = tanhf(a) * PI_F;
    float sn, cs;
    sincosf(a, &sn, &cs);
    ph[(row0 + r) * PP + p] = make_float2(cs, sn);
}

// ---------------------------------------------------------------------------
// Kernel 2: bind. M_c[q][d] = sum_j ph[32c+2j][q] * values[32c+2j+1][d]
// ---------------------------------------------------------------------------
__global__ __launch_bounds__(256) void bind_kernel(
    const float2* __restrict__ ph, const float* __restrict__ values,
    float* __restrict__ M)
{
    __shared__ float phs[16][64];
    const int tid = threadIdx.x;
    const int bid = blockIdx.x;
    const int b  = bid >> 7;
    const int c  = (bid >> 1) & 63;
    const int dh = bid & 1;
    const int base = b * LL;
    const int r0 = 32 * c;

    const float* phf = (const float*)ph;
    #pragma unroll
    for (int k = 0; k < 4; ++k) {
        const int e = tid + k * 256;
        const int j = e >> 6, q = e & 63;
        phs[j][q] = phf[(base + r0 + 2 * j) * 64 + q];
    }
    __syncthreads();

    const int d4 = dh * 128 + (tid & 31) * 4;
    const int qg = tid >> 5;
    float4 acc[8];
    #pragma unroll
    for (int qi = 0; qi < 8; ++qi) acc[qi] = make_float4(0.f,0.f,0.f,0.f);

    #pragma unroll 4
    for (int j = 0; j < 16; ++j) {
        const float4 v = *(const float4*)&values[(base + r0 + 2 * j + 1) * DD + d4];
        #pragma unroll
        for (int qi = 0; qi < 8; ++qi) {
            const float s = phs[j][qg * 8 + qi];
            acc[qi].x += v.x * s; acc[qi].y += v.y * s;
            acc[qi].z += v.z * s; acc[qi].w += v.w * s;
        }
    }
    #pragma unroll
    for (int qi = 0; qi < 8; ++qi) {
        const int q = qg * 8 + qi;
        *(float4*)&M[(((b * NC) + c) * 64 + q) * DD + d4] = acc[qi];
    }
}

// ---------------------------------------------------------------------------
// Kernel 3: prefix. In-place EXCLUSIVE prefix sum over chunk index c.
// ---------------------------------------------------------------------------
__global__ __launch_bounds__(256) void prefix_kernel(float* __restrict__ M)
{
    const int tid = threadIdx.x;
    const int b   = blockIdx.x >> 6;
    const int col = (blockIdx.x & 63) * 256 + tid;
    float run = 0.f;
    #pragma unroll 4
    for (int c = 0; c < NC; ++c) {
        const long a = ((long)(b * NC + c)) * 16384 + col;
        const float tmp = M[a];
        M[a] = run;
        run += tmp;
    }
}

// ---------------------------------------------------------------------------
// Kernel 4: retrieve + LN1 -> rhat (bf16). 8 l-rows/block, grid 512.
// ---------------------------------------------------------------------------
__device__ inline float red32(float v) {
    v += __shfl_xor(v, 16, 32);
    v += __shfl_xor(v, 8, 32);
    v += __shfl_xor(v, 4, 32);
    v += __shfl_xor(v, 2, 32);
    v += __shfl_xor(v, 1, 32);
    return v;
}

__global__ __launch_bounds__(256) void retrieve_kernel(
    const float2* __restrict__ ph, const float* __restrict__ values,
    const float* __restrict__ Mpre,
    const float* __restrict__ ln1_g, const float* __restrict__ ln1_b,
    ushort_t* __restrict__ rhat)
{
    __shared__ float phT[64][10];
    __shared__ float S[16][10];
    __shared__ float ref[8][264];

    const int tid = threadIdx.x;
    const int b   = blockIdx.x >> 8;
    const int lt  = blockIdx.x & 255;
    const int l0  = lt * 8;
    const int base = b * LL;
    const int c     = l0 >> 5;
    const int l0loc = l0 & 31;
    const int jcnt  = l0loc / 2 + 4;

    const float* phf = (const float*)ph;
    #pragma unroll
    for (int k = 0; k < 2; ++k) {
        const int e = tid + k * 256;
        const int r = e >> 6, q = e & 63;
        phT[q][r] = phf[(base + l0 + r) * 64 + q];
    }
    __syncthreads();

    if (tid < 128) {
        const int l = tid & 7, j = tid >> 3;
        const float* ps = &phf[(base + 32 * c + 2 * j) * 64];
        float s = 0.f;
        #pragma unroll 8
        for (int q = 0; q < 64; ++q)
            s += phT[q][l] * ps[q];
        if (2 * j + 1 > l0loc + l) s = 0.f;
        S[j][l] = s;
    }

    const int g = tid >> 6;
    const int d4 = (tid & 63) * 4;
    float4 acc0 = make_float4(0.f,0.f,0.f,0.f);
    float4 acc1 = make_float4(0.f,0.f,0.f,0.f);
    {
        const float* Mc = &Mpre[((long)(b * NC + c)) * 16384 + d4];
        #pragma unroll 8
        for (int q = 0; q < 64; ++q) {
            const float4 m = *(const float4*)&Mc[q * DD];
            const float2 ss = *(const float2*)&phT[q][2 * g];
            acc0.x += m.x * ss.x; acc0.y += m.y * ss.x;
            acc0.z += m.z * ss.x; acc0.w += m.w * ss.x;
            acc1.x += m.x * ss.y; acc1.y += m.y * ss.y;
            acc1.z += m.z * ss.y; acc1.w += m.w * ss.y;
        }
    }
    __syncthreads();

    for (int j = 0; j < jcnt; ++j) {
        const float4 v = *(const float4*)&values[(base + 32 * c + 2 * j + 1) * DD + d4];
        const float2 ss = *(const float2*)&S[j][2 * g];
        acc0.x += v.x * ss.x; acc0.y += v.y * ss.x;
        acc0.z += v.z * ss.x; acc0.w += v.w * ss.x;
        acc1.x += v.x * ss.y; acc1.y += v.y * ss.y;
        acc1.z += v.z * ss.y; acc1.w += v.w * ss.y;
    }

    {
        const float invP = 0.17677669529663687f;
        const int la = l0 + 2 * g;
        int va = (la + 1) / 2; if (va < 1) va = 1;
        const float sc0 = invP * rsqrtf((float)va);
        int vb = (la + 2) / 2; if (vb < 1) vb = 1;
        const float sc1 = invP * rsqrtf((float)vb);
        *(float4*)&ref[2 * g][d4] = make_float4(acc0.x*sc0, acc0.y*sc0, acc0.z*sc0, acc0.w*sc0);
        *(float4*)&ref[2 * g + 1][d4] = make_float4(acc1.x*sc1, acc1.y*sc1, acc1.z*sc1, acc1.w*sc1);
    }
    __syncthreads();

    {
        const long row0 = (long)blockIdx.x * 8;
        const int r = tid >> 5, lane = tid & 31;
        float v[8], s = 0.f, sq = 0.f;
        #pragma unroll
        for (int i = 0; i < 8; ++i) {
            v[i] = ref[r][lane + 32 * i];
            s += v[i]; sq += v[i] * v[i];
        }
        s = red32(s); sq = red32(sq);
        const float m = s * (1.f / 256.f);
        const float inv = rsqrtf(sq * (1.f / 256.f) - m * m + 1e-5f);
        #pragma unroll
        for (int i = 0; i < 8; ++i) {
            const int cc = lane + 32 * i;
            rhat[(row0 + r) * DD + cc] = f2bf((v[i] - m) * inv * ln1_g[cc] + ln1_b[cc]);
        }
    }
}

// ---------------------------------------------------------------------------
// MFMA GEMM: C[4096][N] = A[4096][K](bf16) @ Bt[N][K](bf16)^T + bias.
// BM=16, BN=64, 4 waves. MODE 0: gelu->bf16; 1: bias->f32; 2: bias+resid->f32.
// ---------------------------------------------------------------------------
template<int K, int N, int MODE>
__global__ __launch_bounds__(256) void mfma_gemm(
    const ushort_t* __restrict__ A, const ushort_t* __restrict__ Bt,
    const float* __restrict__ bias, const float* __restrict__ resid,
    void* __restrict__ out)
{
    __shared__ ushort_t As[16][136];
    __shared__ ushort_t Bs[64][136];
    const int tid = threadIdx.x;
    const int mt = blockIdx.x & 255;
    const int nt = blockIdx.x >> 8;
    const int m0 = mt * 16, n0 = nt * 64;
    const int wv = tid >> 6, lane = tid & 63;
    const int qd = lane >> 4, mc = lane & 15;

    f32x4 acc = {0.f, 0.f, 0.f, 0.f};

    const int ar = tid >> 4, ak = (tid & 15) * 8;
    const int bn = tid >> 2, bk = (tid & 3) * 32;

    for (int k0 = 0; k0 < K; k0 += 128) {
        __syncthreads();
        *(uint4*)&As[ar][ak] = *(const uint4*)&A[(long)(m0 + ar) * K + k0 + ak];
        {
            const ushort_t* src = &Bt[(long)(n0 + bn) * K + k0 + bk];
            *(uint4*)&Bs[bn][bk +  0] = *(const uint4*)&src[0];
            *(uint4*)&Bs[bn][bk +  8] = *(const uint4*)&src[8];
            *(uint4*)&Bs[bn][bk + 16] = *(const uint4*)&src[16];
            *(uint4*)&Bs[bn][bk + 24] = *(const uint4*)&src[24];
        }
        __syncthreads();
        #pragma unroll
        for (int ko = 0; ko < 128; ko += 32) {
            const bf16x8 a = *(const bf16x8*)&As[mc][ko + qd * 8];
            const bf16x8 b = *(const bf16x8*)&Bs[wv * 16 + mc][ko + qd * 8];
            acc = __builtin_amdgcn_mfma_f32_16x16x32_bf16(a, b, acc, 0, 0, 0);
        }
    }

    const int nn = n0 + wv * 16 + mc;
    const float bb = bias[nn];
    #pragma unroll
    for (int r = 0; r < 4; ++r) {
        const long row = m0 + qd * 4 + r;
        float v = acc[r] + bb;
        if (MODE == 0) {
            v = 0.5f * v * (1.f + erff(v * 0.70710678118654752f));
            ((ushort_t*)out)[row * N + nn] = f2bf(v);
        } else if (MODE == 1) {
            ((float*)out)[row * N + nn] = v;
        } else {
            ((float*)out)[row * N + nn] = v + resid[row * N + nn];
        }
    }
}

// ---------------------------------------------------------------------------
// LN2: refined (f32) -> shat (bf16). 8 rows/block, grid 512.
// ---------------------------------------------------------------------------
__global__ __launch_bounds__(256) void ln2_kernel(
    const float* __restrict__ refined, const float* __restrict__ ln2_g,
    const float* __restrict__ ln2_b, ushort_t* __restrict__ shat)
{
    const int tid = threadIdx.x;
    const long row = (long)blockIdx.x * 8 + (tid >> 5);
    const int lane = tid & 31;
    float v[8], s = 0.f, sq = 0.f;
    #pragma unroll
    for (int i = 0; i < 8; ++i) {
        v[i] = refined[row * DD + lane + 32 * i];
        s += v[i]; sq += v[i] * v[i];
    }
    s = red32(s); sq = red32(sq);
    const float m = s * (1.f / 256.f);
    const float inv = rsqrtf(sq * (1.f / 256.f) - m * m + 1e-5f);
    #pragma unroll
    for (int i = 0; i < 8; ++i) {
        const int cc = lane + 32 * i;
        shat[row * DD + cc] = f2bf((v[i] - m) * inv * ln2_g[cc] + ln2_b[cc]);
    }
}

// ---------------------------------------------------------------------------
extern "C" void kernel_launch(void* const* d_in, const int* in_sizes, int n_in,
                              void* d_out, int out_size, void* d_ws, size_t ws_size,
                              hipStream_t stream)
{
    const float* x     = (const float*)d_in[0];
    const float* key_W = (const float*)d_in[1];
    const float* key_b = (const float*)d_in[2];
    const float* val_W = (const float*)d_in[3];
    const float* val_b = (const float*)d_in[4];
    const float* ln1_g = (const float*)d_in[5];
    const float* ln1_b = (const float*)d_in[6];
    const float* W1    = (const float*)d_in[7];
    const float* b1    = (const float*)d_in[8];
    const float* W2    = (const float*)d_in[9];
    const float* b2    = (const float*)d_in[10];
    const float* ln2_g = (const float*)d_in[11];
    const float* ln2_b = (const float*)d_in[12];
    const float* Wo    = (const float*)d_in[13];
    const float* bo    = (const float*)d_in[14];
    float* outp = (float*)d_out;

    float* ws = (float*)d_ws;
    float2* ph       = (float2*)ws;                       // 262144 f32 (1 MB)
    float*  values   = ws + 262144;                       // 1048576 f32 (-> refined)
    float*  M        = values + 1048576;                  // 2097152 f32 (-> h_b, shat_b)
    ushort_t* rhat_b = (ushort_t*)(M + 2097152);          // 1048576 us (524288 f32)
    ushort_t* W1t    = (ushort_t*)(M + 2097152 + 524288); // 131072 us
    ushort_t* W2t    = W1t + 131072;                      // 131072 us
    ushort_t* Wot    = W2t + 131072;                      // 65536 us
    ushort_t* valWt  = Wot + 65536;                       // 65536 us
    ushort_t* xb     = valWt + 65536;                     // 1048576 us (2 MB)
    // reuse after retrieve:
    ushort_t* h_b    = (ushort_t*)M;
    ushort_t* shat_b = (ushort_t*)(M + 1048576);
    float* refined   = values;
    // total ws ~ 19 MB

    prep_kernel<<<128, 256, 0, stream>>>(W1, W2, Wo, val_W, x,
                                         W1t, W2t, Wot, valWt, xb);
    encode_key_kernel<<<BB * LL / 8, 256, 0, stream>>>(x, key_W, key_b, ph);
    mfma_gemm<256, 256, 1><<<256 * 4, 256, 0, stream>>>(xb, valWt, val_b, nullptr, values);
    bind_kernel<<<BB * NC * 2, 256, 0, stream>>>(ph, values, M);
    prefix_kernel<<<BB * 64, 256, 0, stream>>>(M);
    retrieve_kernel<<<BB * (LL / 8), 256, 0, stream>>>(ph, values, M,
                                                       ln1_g, ln1_b, rhat_b);
    mfma_gemm<256, 512, 0><<<256 * 8, 256, 0, stream>>>(rhat_b, W1t, b1, nullptr, h_b);
    mfma_gemm<512, 256, 1><<<256 * 4, 256, 0, stream>>>(h_b, W2t, b2, nullptr, refined);
    ln2_kernel<<<BB * LL / 8, 256, 0, stream>>>(refined, ln2_g, ln2_b, shat_b);
    mfma_gemm<256, 256, 2><<<256 * 4, 256, 0, stream>>>(shat_b, Wot, bo, x, outp);
}

// Round 7
// 141.729 us; speedup vs baseline: 1.6972x; 1.1004x over previous
//
#include <hip/hip_runtime.h>
#include <math.h>

#define BB 2
#define LL 2048
#define DD 256
#define PP 32
#define NC 64
#define PI_F 3.14159265358979323846f

typedef __attribute__((ext_vector_type(8))) short bf16x8;
typedef __attribute__((ext_vector_type(4))) float f32x4;
typedef unsigned short ushort_t;
typedef unsigned int uint_t;

__device__ inline ushort_t f2bf(float x) {
    uint_t u = __float_as_uint(x);
    uint_t r = (u + 0x7fffu + ((u >> 16) & 1u)) >> 16;
    return (ushort_t)r;
}

// ---------------------------------------------------------------------------
// Kernel A: prep (weight transposes to bf16 [N][K]) + encode_key (phases).
// blocks 0-31: W1^T; 32-63: W2^T; 64-79: Wo^T; 80-95: val_W^T; 96-607: phases.
// ---------------------------------------------------------------------------
__global__ __launch_bounds__(256) void prep_key_kernel(
    const float* __restrict__ W1, const float* __restrict__ W2,
    const float* __restrict__ Wo, const float* __restrict__ valW,
    const float* __restrict__ x, const float* __restrict__ key_W,
    const float* __restrict__ key_b,
    ushort_t* __restrict__ W1t, ushort_t* __restrict__ W2t,
    ushort_t* __restrict__ Wot, ushort_t* __restrict__ valWt,
    float2* __restrict__ ph)
{
    const int bid = blockIdx.x;
    const int t = threadIdx.x;
    if (bid < 96) {
        __shared__ float T[64][65];
        const float* W; ushort_t* Wt; int K, N, tile;
        if (bid < 32)      { W = W1;   Wt = W1t;   K = 256; N = 512; tile = bid; }
        else if (bid < 64) { W = W2;   Wt = W2t;   K = 512; N = 256; tile = bid - 32; }
        else if (bid < 80) { W = Wo;   Wt = Wot;   K = 256; N = 256; tile = bid - 64; }
        else               { W = valW; Wt = valWt; K = 256; N = 256; tile = bid - 80; }
        const int ntiles = N / 64;
        const int k0 = (tile / ntiles) * 64, n0 = (tile % ntiles) * 64;
        {
            const int rr = t >> 2, cb = (t & 3) * 16;
            #pragma unroll
            for (int i = 0; i < 16; i += 4) {
                const float4 v = *(const float4*)&W[(k0 + rr) * N + n0 + cb + i];
                T[rr][cb + i + 0] = v.x; T[rr][cb + i + 1] = v.y;
                T[rr][cb + i + 2] = v.z; T[rr][cb + i + 3] = v.w;
            }
        }
        __syncthreads();
        {
            const int n = t >> 2, kb = (t & 3) * 16;
            #pragma unroll
            for (int i = 0; i < 16; ++i)
                Wt[(n0 + n) * K + k0 + kb + i] = f2bf(T[kb + i][n]);
        }
    } else {
        __shared__ float xs[256][8];
        const int row0 = (bid - 96) * 8;
        #pragma unroll
        for (int i = 0; i < 8; ++i)
            xs[t][i] = x[(row0 + i) * DD + t];
        __syncthreads();
        const int r = t >> 5, p = t & 31;
        float a = key_b[p];
        #pragma unroll 8
        for (int k = 0; k < DD; ++k)
            a += xs[k][r] * key_W[k * PP + p];
        a = tanhf(a) * PI_F;
        float sn, cs;
        sincosf(a, &sn, &cs);
        ph[(row0 + r) * PP + p] = make_float2(cs, sn);
    }
}

// ---------------------------------------------------------------------------
// Kernel B: valbind. Block = (b, chunk c, d-half dh); grid 256.
// Phase 1 (MFMA): V_odd[j 16][dloc 128] = x[odd rows of chunk] @ valW + val_b
//                 -> values_odd fp32 (global) + VdT bf16 [dloc][j] (LDS)
// Phase 2 (MFMA): M_c[q 64][dloc 128] = phs^T[q][j] @ VdT[dloc][j]^T (K=16 pad 32)
// ---------------------------------------------------------------------------
__global__ __launch_bounds__(256) void valbind_kernel(
    const float* __restrict__ x, const float2* __restrict__ ph,
    const ushort_t* __restrict__ valWt, const float* __restrict__ val_b,
    float* __restrict__ values_odd, float* __restrict__ M)
{
    __shared__ ushort_t xsb[16][264];   // odd-row x tile, bf16 [j][k]
    __shared__ ushort_t VdT[128][40];   // values transposed [dloc][j], 80B rows
    __shared__ ushort_t phsT[64][40];   // shifted phasors [q][j]

    const int tid = threadIdx.x;
    const int bid = blockIdx.x;
    const int b  = bid >> 7;
    const int rem = bid & 127;
    const int c  = rem >> 1;
    const int dh = rem & 1;
    const int base = b * LL;
    const int r0 = 32 * c;

    {   // stage xsb: thread (j = tid>>4, cb = (tid&15)*16)
        const int j = tid >> 4, cb = (tid & 15) * 16;
        const float* src = &x[(long)(base + r0 + 2 * j + 1) * DD + cb];
        ushort_t tmp[16];
        #pragma unroll
        for (int i = 0; i < 4; ++i) {
            const float4 v = *(const float4*)&src[i * 4];
            tmp[i*4+0] = f2bf(v.x); tmp[i*4+1] = f2bf(v.y);
            tmp[i*4+2] = f2bf(v.z); tmp[i*4+3] = f2bf(v.w);
        }
        *(uint4*)&xsb[j][cb]     = *(uint4*)&tmp[0];
        *(uint4*)&xsb[j][cb + 8] = *(uint4*)&tmp[8];
    }
    {   // stage phsT (transpose): thread (j = tid>>4, qb = (tid&15)*4)
        const int j = tid >> 4, qb = (tid & 15) * 4;
        const float4 v = *(const float4*)((const float*)ph +
                              (long)(base + r0 + 2 * j) * 64 + qb);
        phsT[qb + 0][j] = f2bf(v.x);
        phsT[qb + 1][j] = f2bf(v.y);
        phsT[qb + 2][j] = f2bf(v.z);
        phsT[qb + 3][j] = f2bf(v.w);
    }
    // zero K-pad (j = 16..31) of phsT and VdT
    for (int e = tid; e < 64 * 16; e += 256)
        phsT[e >> 4][16 + (e & 15)] = 0;
    for (int e = tid; e < 128 * 16; e += 256)
        VdT[e >> 4][16 + (e & 15)] = 0;
    __syncthreads();

    const int wv = tid >> 6, lane = tid & 63;
    const int qd = lane >> 4, mc = lane & 15;

    // ---- phase 1: values MFMA ----
    f32x4 va0 = {0.f,0.f,0.f,0.f}, va1 = {0.f,0.f,0.f,0.f};
    const int dloc0 = wv * 32 + mc, dloc1 = dloc0 + 16;
    const int n0g = dh * 128 + dloc0, n1g = n0g + 16;
    const ushort_t* B0 = &valWt[(long)n0g * 256];
    const ushort_t* B1 = &valWt[(long)n1g * 256];
    #pragma unroll
    for (int ks = 0; ks < 8; ++ks) {
        const bf16x8 a  = *(const bf16x8*)&xsb[mc][ks * 32 + qd * 8];
        const bf16x8 b0 = *(const bf16x8*)&B0[ks * 32 + qd * 8];
        const bf16x8 b1 = *(const bf16x8*)&B1[ks * 32 + qd * 8];
        va0 = __builtin_amdgcn_mfma_f32_16x16x32_bf16(a, b0, va0, 0, 0, 0);
        va1 = __builtin_amdgcn_mfma_f32_16x16x32_bf16(a, b1, va1, 0, 0, 0);
    }
    {
        const float bb0 = val_b[n0g], bb1 = val_b[n1g];
        #pragma unroll
        for (int r = 0; r < 4; ++r) {
            const int j = qd * 4 + r;
            const float v0 = va0[r] + bb0, v1 = va1[r] + bb1;
            const long rowo = ((long)(b * NC + c) * 16 + j) * DD;
            values_odd[rowo + n0g] = v0;
            values_odd[rowo + n1g] = v1;
            VdT[dloc0][j] = f2bf(v0);
            VdT[dloc1][j] = f2bf(v1);
        }
    }
    __syncthreads();

    // ---- phase 2: bind MFMA (K=32, j 16..31 zeroed) ----
    const bf16x8 a2 = *(const bf16x8*)&phsT[wv * 16 + mc][qd * 8];
    f32x4 macc[8];
    #pragma unroll
    for (int nf = 0; nf < 8; ++nf) {
        f32x4 z = {0.f,0.f,0.f,0.f};
        const bf16x8 b2 = *(const bf16x8*)&VdT[nf * 16 + mc][qd * 8];
        macc[nf] = __builtin_amdgcn_mfma_f32_16x16x32_bf16(a2, b2, z, 0, 0, 0);
    }
    #pragma unroll
    for (int nf = 0; nf < 8; ++nf) {
        #pragma unroll
        for (int r = 0; r < 4; ++r) {
            const int q = wv * 16 + qd * 4 + r;
            M[((long)(b * NC + c) * 64 + q) * 256 + dh * 128 + nf * 16 + mc]
                = macc[nf][r];
        }
    }
}

// ---------------------------------------------------------------------------
// Kernel C: prefix. In-place EXCLUSIVE prefix sum over chunk index c.
// ---------------------------------------------------------------------------
__global__ __launch_bounds__(256) void prefix_kernel(float* __restrict__ M)
{
    const int tid = threadIdx.x;
    const int b   = blockIdx.x >> 6;
    const int col = (blockIdx.x & 63) * 256 + tid;
    float run = 0.f;
    #pragma unroll 4
    for (int c = 0; c < NC; ++c) {
        const long a = ((long)(b * NC + c)) * 16384 + col;
        const float tmp = M[a];
        M[a] = run;
        run += tmp;
    }
}

// ---------------------------------------------------------------------------
// Kernel D: retrieve + LN1 -> rhat (bf16). 8 l-rows/block, grid 512.
// ---------------------------------------------------------------------------
__device__ inline float red32(float v) {
    v += __shfl_xor(v, 16, 32);
    v += __shfl_xor(v, 8, 32);
    v += __shfl_xor(v, 4, 32);
    v += __shfl_xor(v, 2, 32);
    v += __shfl_xor(v, 1, 32);
    return v;
}

__global__ __launch_bounds__(256) void retrieve_kernel(
    const float2* __restrict__ ph, const float* __restrict__ values_odd,
    const float* __restrict__ Mpre,
    const float* __restrict__ ln1_g, const float* __restrict__ ln1_b,
    ushort_t* __restrict__ rhat)
{
    __shared__ float phT[64][10];
    __shared__ float S[16][10];
    __shared__ float ref[8][264];

    const int tid = threadIdx.x;
    const int b   = blockIdx.x >> 8;
    const int lt  = blockIdx.x & 255;
    const int l0  = lt * 8;
    const int base = b * LL;
    const int c     = l0 >> 5;
    const int l0loc = l0 & 31;
    const int jcnt  = l0loc / 2 + 4;

    const float* phf = (const float*)ph;
    #pragma unroll
    for (int k = 0; k < 2; ++k) {
        const int e = tid + k * 256;
        const int r = e >> 6, q = e & 63;
        phT[q][r] = phf[(base + l0 + r) * 64 + q];
    }
    __syncthreads();

    if (tid < 128) {
        const int l = tid & 7, j = tid >> 3;
        const float* ps = &phf[(base + 32 * c + 2 * j) * 64];
        float s = 0.f;
        #pragma unroll 8
        for (int q = 0; q < 64; ++q)
            s += phT[q][l] * ps[q];
        if (2 * j + 1 > l0loc + l) s = 0.f;
        S[j][l] = s;
    }

    const int g = tid >> 6;
    const int d4 = (tid & 63) * 4;
    float4 acc0 = make_float4(0.f,0.f,0.f,0.f);
    float4 acc1 = make_float4(0.f,0.f,0.f,0.f);
    {
        const float* Mc = &Mpre[((long)(b * NC + c)) * 16384 + d4];
        #pragma unroll 8
        for (int q = 0; q < 64; ++q) {
            const float4 m = *(const float4*)&Mc[q * DD];
            const float2 ss = *(const float2*)&phT[q][2 * g];
            acc0.x += m.x * ss.x; acc0.y += m.y * ss.x;
            acc0.z += m.z * ss.x; acc0.w += m.w * ss.x;
            acc1.x += m.x * ss.y; acc1.y += m.y * ss.y;
            acc1.z += m.z * ss.y; acc1.w += m.w * ss.y;
        }
    }
    __syncthreads();

    for (int j = 0; j < jcnt; ++j) {
        const float4 v = *(const float4*)
            &values_odd[((long)(b * NC + c) * 16 + j) * DD + d4];
        const float2 ss = *(const float2*)&S[j][2 * g];
        acc0.x += v.x * ss.x; acc0.y += v.y * ss.x;
        acc0.z += v.z * ss.x; acc0.w += v.w * ss.x;
        acc1.x += v.x * ss.y; acc1.y += v.y * ss.y;
        acc1.z += v.z * ss.y; acc1.w += v.w * ss.y;
    }

    {
        const float invP = 0.17677669529663687f;
        const int la = l0 + 2 * g;
        int va = (la + 1) / 2; if (va < 1) va = 1;
        const float sc0 = invP * rsqrtf((float)va);
        int vb = (la + 2) / 2; if (vb < 1) vb = 1;
        const float sc1 = invP * rsqrtf((float)vb);
        *(float4*)&ref[2 * g][d4] = make_float4(acc0.x*sc0, acc0.y*sc0, acc0.z*sc0, acc0.w*sc0);
        *(float4*)&ref[2 * g + 1][d4] = make_float4(acc1.x*sc1, acc1.y*sc1, acc1.z*sc1, acc1.w*sc1);
    }
    __syncthreads();

    {
        const long row0 = (long)blockIdx.x * 8;
        const int r = tid >> 5, lane = tid & 31;
        float v[8], s = 0.f, sq = 0.f;
        #pragma unroll
        for (int i = 0; i < 8; ++i) {
            v[i] = ref[r][lane + 32 * i];
            s += v[i]; sq += v[i] * v[i];
        }
        s = red32(s); sq = red32(sq);
        const float m = s * (1.f / 256.f);
        const float inv = rsqrtf(sq * (1.f / 256.f) - m * m + 1e-5f);
        #pragma unroll
        for (int i = 0; i < 8; ++i) {
            const int cc = lane + 32 * i;
            rhat[(row0 + r) * DD + cc] = f2bf((v[i] - m) * inv * ln1_g[cc] + ln1_b[cc]);
        }
    }
}

// ---------------------------------------------------------------------------
// MFMA GEMM (gemm1 / gemm3): C[4096][N] = A @ Bt^T + bias (+resid).
// MODE 0: gelu->bf16; MODE 2: bias+resid->f32.
// ---------------------------------------------------------------------------
template<int K, int N, int MODE>
__global__ __launch_bounds__(256) void mfma_gemm(
    const ushort_t* __restrict__ A, const ushort_t* __restrict__ Bt,
    const float* __restrict__ bias, const float* __restrict__ resid,
    void* __restrict__ out)
{
    __shared__ ushort_t As[16][136];
    __shared__ ushort_t Bs[64][136];
    const int tid = threadIdx.x;
    const int mt = blockIdx.x & 255;
    const int nt = blockIdx.x >> 8;
    const int m0 = mt * 16, n0 = nt * 64;
    const int wv = tid >> 6, lane = tid & 63;
    const int qd = lane >> 4, mc = lane & 15;

    f32x4 acc = {0.f, 0.f, 0.f, 0.f};

    const int ar = tid >> 4, ak = (tid & 15) * 8;
    const int bn = tid >> 2, bk = (tid & 3) * 32;

    for (int k0 = 0; k0 < K; k0 += 128) {
        __syncthreads();
        *(uint4*)&As[ar][ak] = *(const uint4*)&A[(long)(m0 + ar) * K + k0 + ak];
        {
            const ushort_t* src = &Bt[(long)(n0 + bn) * K + k0 + bk];
            *(uint4*)&Bs[bn][bk +  0] = *(const uint4*)&src[0];
            *(uint4*)&Bs[bn][bk +  8] = *(const uint4*)&src[8];
            *(uint4*)&Bs[bn][bk + 16] = *(const uint4*)&src[16];
            *(uint4*)&Bs[bn][bk + 24] = *(const uint4*)&src[24];
        }
        __syncthreads();
        #pragma unroll
        for (int ko = 0; ko < 128; ko += 32) {
            const bf16x8 a = *(const bf16x8*)&As[mc][ko + qd * 8];
            const bf16x8 b = *(const bf16x8*)&Bs[wv * 16 + mc][ko + qd * 8];
            acc = __builtin_amdgcn_mfma_f32_16x16x32_bf16(a, b, acc, 0, 0, 0);
        }
    }

    const int nn = n0 + wv * 16 + mc;
    const float bb = bias[nn];
    #pragma unroll
    for (int r = 0; r < 4; ++r) {
        const long row = m0 + qd * 4 + r;
        float v = acc[r] + bb;
        if (MODE == 0) {
            v = 0.5f * v * (1.f + erff(v * 0.70710678118654752f));
            ((ushort_t*)out)[row * N + nn] = f2bf(v);
        } else {
            ((float*)out)[row * N + nn] = v + resid[row * N + nn];
        }
    }
}

// ---------------------------------------------------------------------------
// Kernel F: gemm2 + LN2 fused. BM=16, BN=256 (full rows), K=512; grid 256.
// refined = h @ W2 + b2, then LN2 in epilogue -> shat (bf16).
// ---------------------------------------------------------------------------
__global__ __launch_bounds__(256) void gemm2ln_kernel(
    const ushort_t* __restrict__ h, const ushort_t* __restrict__ W2t,
    const float* __restrict__ b2, const float* __restrict__ ln2_g,
    const float* __restrict__ ln2_b, ushort_t* __restrict__ shat)
{
    __shared__ ushort_t As[16][72];
    __shared__ ushort_t Bs[256][72];
    __shared__ float Ct[16][264];

    const int tid = threadIdx.x;
    const int m0 = blockIdx.x * 16;
    const int wv = tid >> 6, lane = tid & 63;
    const int qd = lane >> 4, mc = lane & 15;

    f32x4 acc[4];
    #pragma unroll
    for (int nf = 0; nf < 4; ++nf) acc[nf] = (f32x4){0.f,0.f,0.f,0.f};

    const int sr = tid >> 3, sk = (tid & 7) * 8;

    for (int k0 = 0; k0 < 512; k0 += 64) {
        __syncthreads();
        if (tid < 128)
            *(uint4*)&As[sr][sk] = *(const uint4*)&h[(long)(m0 + sr) * 512 + k0 + sk];
        #pragma unroll
        for (int rr = 0; rr < 8; ++rr) {
            const int n = rr * 32 + (tid >> 3);
            *(uint4*)&Bs[n][sk] = *(const uint4*)&W2t[(long)n * 512 + k0 + sk];
        }
        __syncthreads();
        #pragma unroll
        for (int ks = 0; ks < 2; ++ks) {
            const bf16x8 a = *(const bf16x8*)&As[mc][ks * 32 + qd * 8];
            #pragma unroll
            for (int nf = 0; nf < 4; ++nf) {
                const bf16x8 b = *(const bf16x8*)&Bs[wv * 64 + nf * 16 + mc][ks * 32 + qd * 8];
                acc[nf] = __builtin_amdgcn_mfma_f32_16x16x32_bf16(a, b, acc[nf], 0, 0, 0);
            }
        }
    }

    #pragma unroll
    for (int nf = 0; nf < 4; ++nf) {
        const int n = wv * 64 + nf * 16 + mc;
        const float bb = b2[n];
        #pragma unroll
        for (int r = 0; r < 4; ++r)
            Ct[qd * 4 + r][n] = acc[nf][r] + bb;
    }
    __syncthreads();

    // LN2: row = tid>>4 (16 rows), 16 threads per row, 16 cols each
    {
        const int row = tid >> 4, cg = (tid & 15) * 16;
        float s = 0.f, sq = 0.f;
        #pragma unroll
        for (int i = 0; i < 16; ++i) {
            const float v = Ct[row][cg + i];
            s += v; sq += v * v;
        }
        s  += __shfl_xor(s, 1, 16);  sq += __shfl_xor(sq, 1, 16);
        s  += __shfl_xor(s, 2, 16);  sq += __shfl_xor(sq, 2, 16);
        s  += __shfl_xor(s, 4, 16);  sq += __shfl_xor(sq, 4, 16);
        s  += __shfl_xor(s, 8, 16);  sq += __shfl_xor(sq, 8, 16);
        const float m = s * (1.f / 256.f);
        const float inv = rsqrtf(sq * (1.f / 256.f) - m * m + 1e-5f);
        #pragma unroll
        for (int i = 0; i < 16; ++i) {
            const int cc = cg + i;
            shat[(long)(m0 + row) * DD + cc] =
                f2bf((Ct[row][cc] - m) * inv * ln2_g[cc] + ln2_b[cc]);
        }
    }
}

// ---------------------------------------------------------------------------
extern "C" void kernel_launch(void* const* d_in, const int* in_sizes, int n_in,
                              void* d_out, int out_size, void* d_ws, size_t ws_size,
                              hipStream_t stream)
{
    const float* x     = (const float*)d_in[0];
    const float* key_W = (const float*)d_in[1];
    const float* key_b = (const float*)d_in[2];
    const float* val_W = (const float*)d_in[3];
    const float* val_b = (const float*)d_in[4];
    const float* ln1_g = (const float*)d_in[5];
    const float* ln1_b = (const float*)d_in[6];
    const float* W1    = (const float*)d_in[7];
    const float* b1    = (const float*)d_in[8];
    const float* W2    = (const float*)d_in[9];
    const float* b2    = (const float*)d_in[10];
    const float* ln2_g = (const float*)d_in[11];
    const float* ln2_b = (const float*)d_in[12];
    const float* Wo    = (const float*)d_in[13];
    const float* bo    = (const float*)d_in[14];
    float* outp = (float*)d_out;

    float* ws = (float*)d_ws;
    float2* ph         = (float2*)ws;                 // 262144 f32 (1 MB)
    float*  values_odd = ws + 262144;                 // 524288 f32 (2 MB)
    float*  M          = values_odd + 524288;         // 2097152 f32 (8 MB)
    ushort_t* rhat_b   = (ushort_t*)(M + 2097152);    // 1048576 us (2 MB)
    ushort_t* W1t      = (ushort_t*)(M + 2097152 + 524288);
    ushort_t* W2t      = W1t + 131072;
    ushort_t* Wot      = W2t + 131072;
    ushort_t* valWt    = Wot + 65536;
    // reuse M after retrieve:
    ushort_t* h_b      = (ushort_t*)M;                // 4096x512 bf16 (4 MB)
    ushort_t* shat_b   = (ushort_t*)(M + 1048576);    // 4096x256 bf16 (2 MB)

    prep_key_kernel<<<608, 256, 0, stream>>>(W1, W2, Wo, val_W, x, key_W, key_b,
                                             W1t, W2t, Wot, valWt, ph);
    valbind_kernel<<<256, 256, 0, stream>>>(x, ph, valWt, val_b, values_odd, M);
    prefix_kernel<<<BB * 64, 256, 0, stream>>>(M);
    retrieve_kernel<<<BB * (LL / 8), 256, 0, stream>>>(ph, values_odd, M,
                                                       ln1_g, ln1_b, rhat_b);
    mfma_gemm<256, 512, 0><<<256 * 8, 256, 0, stream>>>(rhat_b, W1t, b1, nullptr, h_b);
    gemm2ln_kernel<<<256, 256, 0, stream>>>(h_b, W2t, b2, ln2_g, ln2_b, shat_b);
    mfma_gemm<256, 256, 2><<<256 * 4, 256, 0, stream>>>(shat_b, Wot, bo, x, outp);
}

// Round 8
// 133.147 us; speedup vs baseline: 1.8066x; 1.0645x over previous
//
#include <hip/hip_runtime.h>
#include <math.h>

#define BB 2
#define LL 2048
#define DD 256
#define PP 32
#define NC 64
#define PI_F 3.14159265358979323846f

typedef __attribute__((ext_vector_type(8))) short bf16x8;
typedef __attribute__((ext_vector_type(4))) float f32x4;
typedef unsigned short ushort_t;
typedef unsigned int uint_t;

__device__ inline ushort_t f2bf(float x) {
    uint_t u = __float_as_uint(x);
    uint_t r = (u + 0x7fffu + ((u >> 16) & 1u)) >> 16;
    return (ushort_t)r;
}

// ---------------------------------------------------------------------------
// Kernel A: prep (weight transposes to bf16 [N][K]) + encode_key (phases).
// blocks 0-31: W1^T; 32-63: W2^T; 64-79: Wo^T; 80-95: val_W^T; 96-607: phases.
// ---------------------------------------------------------------------------
__global__ __launch_bounds__(256) void prep_key_kernel(
    const float* __restrict__ W1, const float* __restrict__ W2,
    const float* __restrict__ Wo, const float* __restrict__ valW,
    const float* __restrict__ x, const float* __restrict__ key_W,
    const float* __restrict__ key_b,
    ushort_t* __restrict__ W1t, ushort_t* __restrict__ W2t,
    ushort_t* __restrict__ Wot, ushort_t* __restrict__ valWt,
    float2* __restrict__ ph)
{
    const int bid = blockIdx.x;
    const int t = threadIdx.x;
    if (bid < 96) {
        __shared__ float T[64][65];
        const float* W; ushort_t* Wt; int K, N, tile;
        if (bid < 32)      { W = W1;   Wt = W1t;   K = 256; N = 512; tile = bid; }
        else if (bid < 64) { W = W2;   Wt = W2t;   K = 512; N = 256; tile = bid - 32; }
        else if (bid < 80) { W = Wo;   Wt = Wot;   K = 256; N = 256; tile = bid - 64; }
        else               { W = valW; Wt = valWt; K = 256; N = 256; tile = bid - 80; }
        const int ntiles = N / 64;
        const int k0 = (tile / ntiles) * 64, n0 = (tile % ntiles) * 64;
        {
            const int rr = t >> 2, cb = (t & 3) * 16;
            #pragma unroll
            for (int i = 0; i < 16; i += 4) {
                const float4 v = *(const float4*)&W[(k0 + rr) * N + n0 + cb + i];
                T[rr][cb + i + 0] = v.x; T[rr][cb + i + 1] = v.y;
                T[rr][cb + i + 2] = v.z; T[rr][cb + i + 3] = v.w;
            }
        }
        __syncthreads();
        {
            const int n = t >> 2, kb = (t & 3) * 16;
            #pragma unroll
            for (int i = 0; i < 16; ++i)
                Wt[(n0 + n) * K + k0 + kb + i] = f2bf(T[kb + i][n]);
        }
    } else {
        __shared__ float xs[256][8];
        __shared__ float kw[256][33];
        const int row0 = (bid - 96) * 8;
        #pragma unroll
        for (int i = 0; i < 8; ++i)
            xs[t][i] = x[(row0 + i) * DD + t];
        #pragma unroll
        for (int p4 = 0; p4 < 8; ++p4) {
            const int idx4 = p4 * 256 + t;
            const int k = idx4 >> 3, pc = (idx4 & 7) * 4;
            const float4 v = *(const float4*)&key_W[k * 32 + pc];
            kw[k][pc + 0] = v.x; kw[k][pc + 1] = v.y;
            kw[k][pc + 2] = v.z; kw[k][pc + 3] = v.w;
        }
        __syncthreads();
        const int r = t >> 5, p = t & 31;
        float a = key_b[p];
        #pragma unroll 8
        for (int k = 0; k < DD; ++k)
            a += xs[k][r] * kw[k][p];
        a = tanhf(a) * PI_F;
        float sn, cs;
        sincosf(a, &sn, &cs);
        ph[(row0 + r) * PP + p] = make_float2(cs, sn);
    }
}

// ---------------------------------------------------------------------------
// Kernel B: valbind. Block = (b, chunk c, d-half dh); grid 256.
// Phase 1 (MFMA): V_odd[j 16][dloc 128] = x[odd rows] @ valW + val_b
//                 -> VdT bf16 [dloc][j] (LDS), dumped as VoddT [c][d][j] bf16.
// Phase 2 (MFMA): M_c[q][dloc] -> LDS [dloc][q] -> Mt [c][d][q] fp32 (coalesced).
// ---------------------------------------------------------------------------
__global__ __launch_bounds__(256) void valbind_kernel(
    const float* __restrict__ x, const float2* __restrict__ ph,
    const ushort_t* __restrict__ valWt, const float* __restrict__ val_b,
    ushort_t* __restrict__ VoddT, float* __restrict__ Mt)
{
    __shared__ ushort_t xsb[16][264];   // odd-row x tile, bf16 [j][k]
    __shared__ ushort_t VdT[128][40];   // values^T [dloc][j] bf16 (pad 40)
    __shared__ ushort_t phsT[64][40];   // shifted phasors [q][j] bf16
    __shared__ float    Ms[128][68];    // M^T [dloc][q] fp32 (pad 68, 16B-aligned)

    const int tid = threadIdx.x;
    const int bid = blockIdx.x;
    const int b  = bid >> 7;
    const int rem = bid & 127;
    const int c  = rem >> 1;
    const int dh = rem & 1;
    const int base = b * LL;
    const int r0 = 32 * c;

    {   // stage xsb
        const int j = tid >> 4, cb = (tid & 15) * 16;
        const float* src = &x[(long)(base + r0 + 2 * j + 1) * DD + cb];
        ushort_t tmp[16];
        #pragma unroll
        for (int i = 0; i < 4; ++i) {
            const float4 v = *(const float4*)&src[i * 4];
            tmp[i*4+0] = f2bf(v.x); tmp[i*4+1] = f2bf(v.y);
            tmp[i*4+2] = f2bf(v.z); tmp[i*4+3] = f2bf(v.w);
        }
        *(uint4*)&xsb[j][cb]     = *(uint4*)&tmp[0];
        *(uint4*)&xsb[j][cb + 8] = *(uint4*)&tmp[8];
    }
    {   // stage phsT (transpose)
        const int j = tid >> 4, qb = (tid & 15) * 4;
        const float4 v = *(const float4*)((const float*)ph +
                              (long)(base + r0 + 2 * j) * 64 + qb);
        phsT[qb + 0][j] = f2bf(v.x);
        phsT[qb + 1][j] = f2bf(v.y);
        phsT[qb + 2][j] = f2bf(v.z);
        phsT[qb + 3][j] = f2bf(v.w);
    }
    for (int e = tid; e < 64 * 16; e += 256)
        phsT[e >> 4][16 + (e & 15)] = 0;
    for (int e = tid; e < 128 * 16; e += 256)
        VdT[e >> 4][16 + (e & 15)] = 0;
    __syncthreads();

    const int wv = tid >> 6, lane = tid & 63;
    const int qd = lane >> 4, mc = lane & 15;

    // ---- phase 1: values MFMA ----
    f32x4 va0 = {0.f,0.f,0.f,0.f}, va1 = {0.f,0.f,0.f,0.f};
    const int dloc0 = wv * 32 + mc, dloc1 = dloc0 + 16;
    const int n0g = dh * 128 + dloc0, n1g = n0g + 16;
    const ushort_t* B0 = &valWt[(long)n0g * 256];
    const ushort_t* B1 = &valWt[(long)n1g * 256];
    #pragma unroll
    for (int ks = 0; ks < 8; ++ks) {
        const bf16x8 a  = *(const bf16x8*)&xsb[mc][ks * 32 + qd * 8];
        const bf16x8 b0 = *(const bf16x8*)&B0[ks * 32 + qd * 8];
        const bf16x8 b1 = *(const bf16x8*)&B1[ks * 32 + qd * 8];
        va0 = __builtin_amdgcn_mfma_f32_16x16x32_bf16(a, b0, va0, 0, 0, 0);
        va1 = __builtin_amdgcn_mfma_f32_16x16x32_bf16(a, b1, va1, 0, 0, 0);
    }
    {
        const float bb0 = val_b[n0g], bb1 = val_b[n1g];
        #pragma unroll
        for (int r = 0; r < 4; ++r) {
            const int j = qd * 4 + r;
            VdT[dloc0][j] = f2bf(va0[r] + bb0);
            VdT[dloc1][j] = f2bf(va1[r] + bb1);
        }
    }
    __syncthreads();

    // ---- phase 2: bind MFMA (K=32, j 16..31 zeroed) ----
    const bf16x8 a2 = *(const bf16x8*)&phsT[wv * 16 + mc][qd * 8];
    f32x4 macc[8];
    #pragma unroll
    for (int nf = 0; nf < 8; ++nf) {
        f32x4 z = {0.f,0.f,0.f,0.f};
        const bf16x8 b2 = *(const bf16x8*)&VdT[nf * 16 + mc][qd * 8];
        macc[nf] = __builtin_amdgcn_mfma_f32_16x16x32_bf16(a2, b2, z, 0, 0, 0);
    }
    // C[q][dloc] -> Ms[dloc][q]
    #pragma unroll
    for (int nf = 0; nf < 8; ++nf) {
        #pragma unroll
        for (int r = 0; r < 4; ++r) {
            const int q = wv * 16 + qd * 4 + r;
            Ms[nf * 16 + mc][q] = macc[nf][r];
        }
    }
    __syncthreads();

    // coalesced dumps
    {
        float* dst = &Mt[((long)(b * NC + c) * 256 + dh * 128) * 64];
        #pragma unroll
        for (int p = 0; p < 8; ++p) {
            const int idx4 = p * 256 + tid;
            const int dloc = idx4 >> 4, q4 = (idx4 & 15) * 4;
            const float4 v = *(const float4*)&Ms[dloc][q4];
            *(float4*)&dst[dloc * 64 + q4] = v;
        }
    }
    if (tid < 128) {
        ushort_t* vd = &VoddT[((long)(b * NC + c) * 256 + dh * 128 + tid) * 16];
        *(uint4*)&vd[0] = *(const uint4*)&VdT[tid][0];
        *(uint4*)&vd[8] = *(const uint4*)&VdT[tid][8];
    }
}

// ---------------------------------------------------------------------------
// Kernel C: prefix. EXCLUSIVE scan of Mt over chunk c, in place.
// 4-way segmented: grid 512 (2b x 256 colgroups), block = 64 cols x 4 segs.
// ---------------------------------------------------------------------------
__global__ __launch_bounds__(256) void prefix_kernel(float* __restrict__ M)
{
    __shared__ float segsum[4][64];
    const int tid = threadIdx.x;
    const int b  = blockIdx.x >> 8;
    const int cg = blockIdx.x & 255;
    const int col = cg * 64 + (tid & 63);
    const int seg = tid >> 6;
    const long base = (long)b * NC * 16384 + col;

    float v[16], s = 0.f;
    #pragma unroll
    for (int i = 0; i < 16; ++i) {
        v[i] = M[base + (long)(seg * 16 + i) * 16384];
        s += v[i];
    }
    segsum[seg][tid & 63] = s;
    __syncthreads();
    float run = 0.f;
    #pragma unroll
    for (int sg = 0; sg < 3; ++sg)
        if (sg < seg) run += segsum[sg][tid & 63];
    #pragma unroll
    for (int i = 0; i < 16; ++i) {
        const long a = base + (long)(seg * 16 + i) * 16384;
        M[a] = run;
        run += v[i];
    }
}

// ---------------------------------------------------------------------------
// Kernel D: retrieve (MFMA) + LN1 -> rhat (bf16).
// Grid 256: block = (b, chunk c, half h) -> 16 l-rows, full 256 d.
//   main: C[l][d] = phi_l[q] . Mpre[c][d][q]        (K=64, 2 MFMA steps)
//   S:    S[l][j] = phi_l[q] . phis_j[q]            (K=64)
//   corr: C[l][d] += P[l][j] . VoddT[c][d][j]       (K=16 pad 32)
// ---------------------------------------------------------------------------
__global__ __launch_bounds__(256) void retrieve_kernel(
    const float* __restrict__ ph, const float* __restrict__ Mpre,
    const ushort_t* __restrict__ VoddT,
    const float* __restrict__ ln1_g, const float* __restrict__ ln1_b,
    ushort_t* __restrict__ rhat)
{
    __shared__ ushort_t Bs_m[256][72];  // Mpre^T bf16 [d][q]
    __shared__ ushort_t Bs_v[256][32];  // Vodd^T bf16 [d][j] (j-pad zeroed)
    __shared__ ushort_t As_ph[16][72];  // phi rows  [l][q]
    __shared__ ushort_t Bs_sh[16][72];  // shifted phi rows [j][q]
    __shared__ ushort_t As_p[16][32];   // masked scores [l][j] (pad zeroed)
    __shared__ float    ref[16][264];

    const int tid = threadIdx.x;
    const int b = blockIdx.x >> 7;
    const int c = (blockIdx.x >> 1) & 63;
    const int h = blockIdx.x & 1;
    const int l0g = 32 * c + 16 * h;
    const long rowbase = (long)b * LL + l0g;

    {   // stage Bs_m (coalesced f32 reads, bf16 LDS rows)
        const float* src = &Mpre[(long)(b * NC + c) * 16384];
        #pragma unroll
        for (int p = 0; p < 16; ++p) {
            const int idx4 = p * 256 + tid;
            const int d = idx4 >> 4, q4 = (idx4 & 15) * 4;
            const float4 v = *(const float4*)&src[idx4 * 4];
            ushort_t tmp[4] = {f2bf(v.x), f2bf(v.y), f2bf(v.z), f2bf(v.w)};
            *(uint2*)&Bs_m[d][q4] = *(uint2*)tmp;
        }
    }
    {   // stage As_ph + Bs_sh
        const int r = tid >> 4, q4 = (tid & 15) * 4;
        const float4 v = *(const float4*)&ph[(rowbase + r) * 64 + q4];
        ushort_t t0[4] = {f2bf(v.x), f2bf(v.y), f2bf(v.z), f2bf(v.w)};
        *(uint2*)&As_ph[r][q4] = *(uint2*)t0;
        const float4 w = *(const float4*)&ph[((long)b * LL + 32 * c + 2 * r) * 64 + q4];
        ushort_t t1[4] = {f2bf(w.x), f2bf(w.y), f2bf(w.z), f2bf(w.w)};
        *(uint2*)&Bs_sh[r][q4] = *(uint2*)t1;
    }
    {   // stage Bs_v + zero pads
        const ushort_t* src = &VoddT[(long)(b * NC + c) * 4096];
        const int j0 = (tid & 1) * 8;
        *(uint4*)&Bs_v[tid >> 1][j0] = *(const uint4*)&src[tid * 8];
        *(uint4*)&Bs_v[(tid + 256) >> 1][j0] = *(const uint4*)&src[(tid + 256) * 8];
        *(uint4*)&Bs_v[tid][16] = make_uint4(0, 0, 0, 0);
        *(uint4*)&Bs_v[tid][24] = make_uint4(0, 0, 0, 0);
        As_p[tid >> 4][16 + (tid & 15)] = 0;
    }
    __syncthreads();

    const int wv = tid >> 6, lane = tid & 63;
    const int qd = lane >> 4, mc = lane & 15;

    // ---- S scores (all waves compute; wave 0 writes masked bf16) ----
    {
        f32x4 sacc = {0.f, 0.f, 0.f, 0.f};
        #pragma unroll
        for (int ks = 0; ks < 2; ++ks) {
            const bf16x8 a  = *(const bf16x8*)&As_ph[mc][ks * 32 + qd * 8];
            const bf16x8 bb = *(const bf16x8*)&Bs_sh[mc][ks * 32 + qd * 8];
            sacc = __builtin_amdgcn_mfma_f32_16x16x32_bf16(a, bb, sacc, 0, 0, 0);
        }
        if (wv == 0) {
            #pragma unroll
            for (int r = 0; r < 4; ++r) {
                const int l = qd * 4 + r;
                As_p[l][mc] = (2 * mc + 1 <= 16 * h + l) ? f2bf(sacc[r])
                                                         : (ushort_t)0;
            }
        }
    }

    // ---- main contraction ----
    f32x4 acc[4];
    #pragma unroll
    for (int i = 0; i < 4; ++i) acc[i] = (f32x4){0.f, 0.f, 0.f, 0.f};
    #pragma unroll
    for (int i = 0; i < 4; ++i) {
        const int d0 = wv * 64 + i * 16;
        #pragma unroll
        for (int ks = 0; ks < 2; ++ks) {
            const bf16x8 a  = *(const bf16x8*)&As_ph[mc][ks * 32 + qd * 8];
            const bf16x8 bb = *(const bf16x8*)&Bs_m[d0 + mc][ks * 32 + qd * 8];
            acc[i] = __builtin_amdgcn_mfma_f32_16x16x32_bf16(a, bb, acc[i], 0, 0, 0);
        }
    }
    __syncthreads();   // As_p ready

    // ---- within-chunk correction ----
    {
        const bf16x8 a2 = *(const bf16x8*)&As_p[mc][qd * 8];
        #pragma unroll
        for (int i = 0; i < 4; ++i) {
            const int d0 = wv * 64 + i * 16;
            const bf16x8 b2 = *(const bf16x8*)&Bs_v[d0 + mc][qd * 8];
            acc[i] = __builtin_amdgcn_mfma_f32_16x16x32_bf16(a2, b2, acc[i], 0, 0, 0);
        }
    }

    // ---- scale -> ref ----
    #pragma unroll
    for (int r = 0; r < 4; ++r) {
        const int l = qd * 4 + r;
        int va = (l0g + l + 1) >> 1; if (va < 1) va = 1;
        const float sc = 0.17677669529663687f * rsqrtf((float)va);
        #pragma unroll
        for (int i = 0; i < 4; ++i)
            ref[l][wv * 64 + i * 16 + mc] = acc[i][r] * sc;
    }
    __syncthreads();

    // ---- LN1 (16 rows x 16 threads) -> rhat bf16 ----
    {
        const int row = tid >> 4, cg = (tid & 15) * 16;
        float s = 0.f, sq = 0.f;
        #pragma unroll
        for (int i = 0; i < 16; ++i) {
            const float v = ref[row][cg + i];
            s += v; sq += v * v;
        }
        s += __shfl_xor(s, 1, 16);  sq += __shfl_xor(sq, 1, 16);
        s += __shfl_xor(s, 2, 16);  sq += __shfl_xor(sq, 2, 16);
        s += __shfl_xor(s, 4, 16);  sq += __shfl_xor(sq, 4, 16);
        s += __shfl_xor(s, 8, 16);  sq += __shfl_xor(sq, 8, 16);
        const float m = s * (1.f / 256.f);
        const float inv = rsqrtf(sq * (1.f / 256.f) - m * m + 1e-5f);
        ushort_t o16[16];
        #pragma unroll
        for (int i = 0; i < 16; ++i) {
            const int cc = cg + i;
            o16[i] = f2bf((ref[row][cc] - m) * inv * ln1_g[cc] + ln1_b[cc]);
        }
        ushort_t* dst = &rhat[(rowbase + row) * DD + cg];
        *(uint4*)&dst[0] = *(uint4*)&o16[0];
        *(uint4*)&dst[8] = *(uint4*)&o16[8];
    }
}

// ---------------------------------------------------------------------------
// MFMA GEMM (gemm1 / gemm3): C[4096][N] = A @ Bt^T + bias (+resid).
// MODE 0: gelu->bf16; MODE 2: bias+resid->f32.
// ---------------------------------------------------------------------------
template<int K, int N, int MODE>
__global__ __launch_bounds__(256) void mfma_gemm(
    const ushort_t* __restrict__ A, const ushort_t* __restrict__ Bt,
    const float* __restrict__ bias, const float* __restrict__ resid,
    void* __restrict__ out)
{
    __shared__ ushort_t As[16][136];
    __shared__ ushort_t Bs[64][136];
    const int tid = threadIdx.x;
    const int mt = blockIdx.x & 255;
    const int nt = blockIdx.x >> 8;
    const int m0 = mt * 16, n0 = nt * 64;
    const int wv = tid >> 6, lane = tid & 63;
    const int qd = lane >> 4, mc = lane & 15;

    f32x4 acc = {0.f, 0.f, 0.f, 0.f};

    const int ar = tid >> 4, ak = (tid & 15) * 8;
    const int bn = tid >> 2, bk = (tid & 3) * 32;

    for (int k0 = 0; k0 < K; k0 += 128) {
        __syncthreads();
        *(uint4*)&As[ar][ak] = *(const uint4*)&A[(long)(m0 + ar) * K + k0 + ak];
        {
            const ushort_t* src = &Bt[(long)(n0 + bn) * K + k0 + bk];
            *(uint4*)&Bs[bn][bk +  0] = *(const uint4*)&src[0];
            *(uint4*)&Bs[bn][bk +  8] = *(const uint4*)&src[8];
            *(uint4*)&Bs[bn][bk + 16] = *(const uint4*)&src[16];
            *(uint4*)&Bs[bn][bk + 24] = *(const uint4*)&src[24];
        }
        __syncthreads();
        #pragma unroll
        for (int ko = 0; ko < 128; ko += 32) {
            const bf16x8 a = *(const bf16x8*)&As[mc][ko + qd * 8];
            const bf16x8 b = *(const bf16x8*)&Bs[wv * 16 + mc][ko + qd * 8];
            acc = __builtin_amdgcn_mfma_f32_16x16x32_bf16(a, b, acc, 0, 0, 0);
        }
    }

    const int nn = n0 + wv * 16 + mc;
    const float bb = bias[nn];
    #pragma unroll
    for (int r = 0; r < 4; ++r) {
        const long row = m0 + qd * 4 + r;
        float v = acc[r] + bb;
        if (MODE == 0) {
            v = 0.5f * v * (1.f + erff(v * 0.70710678118654752f));
            ((ushort_t*)out)[row * N + nn] = f2bf(v);
        } else {
            ((float*)out)[row * N + nn] = v + resid[row * N + nn];
        }
    }
}

// ---------------------------------------------------------------------------
// Kernel F: gemm2 + LN2 fused. BM=16, BN=256, K=512; grid 256.
// ---------------------------------------------------------------------------
__global__ __launch_bounds__(256) void gemm2ln_kernel(
    const ushort_t* __restrict__ h, const ushort_t* __restrict__ W2t,
    const float* __restrict__ b2, const float* __restrict__ ln2_g,
    const float* __restrict__ ln2_b, ushort_t* __restrict__ shat)
{
    __shared__ ushort_t As[16][72];
    __shared__ ushort_t Bs[256][72];
    __shared__ float Ct[16][264];

    const int tid = threadIdx.x;
    const int m0 = blockIdx.x * 16;
    const int wv = tid >> 6, lane = tid & 63;
    const int qd = lane >> 4, mc = lane & 15;

    f32x4 acc[4];
    #pragma unroll
    for (int nf = 0; nf < 4; ++nf) acc[nf] = (f32x4){0.f,0.f,0.f,0.f};

    const int sr = tid >> 3, sk = (tid & 7) * 8;

    for (int k0 = 0; k0 < 512; k0 += 64) {
        __syncthreads();
        if (tid < 128)
            *(uint4*)&As[sr][sk] = *(const uint4*)&h[(long)(m0 + sr) * 512 + k0 + sk];
        #pragma unroll
        for (int rr = 0; rr < 8; ++rr) {
            const int n = rr * 32 + (tid >> 3);
            *(uint4*)&Bs[n][sk] = *(const uint4*)&W2t[(long)n * 512 + k0 + sk];
        }
        __syncthreads();
        #pragma unroll
        for (int ks = 0; ks < 2; ++ks) {
            const bf16x8 a = *(const bf16x8*)&As[mc][ks * 32 + qd * 8];
            #pragma unroll
            for (int nf = 0; nf < 4; ++nf) {
                const bf16x8 b = *(const bf16x8*)&Bs[wv * 64 + nf * 16 + mc][ks * 32 + qd * 8];
                acc[nf] = __builtin_amdgcn_mfma_f32_16x16x32_bf16(a, b, acc[nf], 0, 0, 0);
            }
        }
    }

    #pragma unroll
    for (int nf = 0; nf < 4; ++nf) {
        const int n = wv * 64 + nf * 16 + mc;
        const float bb = b2[n];
        #pragma unroll
        for (int r = 0; r < 4; ++r)
            Ct[qd * 4 + r][n] = acc[nf][r] + bb;
    }
    __syncthreads();

    {
        const int row = tid >> 4, cg = (tid & 15) * 16;
        float s = 0.f, sq = 0.f;
        #pragma unroll
        for (int i = 0; i < 16; ++i) {
            const float v = Ct[row][cg + i];
            s += v; sq += v * v;
        }
        s  += __shfl_xor(s, 1, 16);  sq += __shfl_xor(sq, 1, 16);
        s  += __shfl_xor(s, 2, 16);  sq += __shfl_xor(sq, 2, 16);
        s  += __shfl_xor(s, 4, 16);  sq += __shfl_xor(sq, 4, 16);
        s  += __shfl_xor(s, 8, 16);  sq += __shfl_xor(sq, 8, 16);
        const float m = s * (1.f / 256.f);
        const float inv = rsqrtf(sq * (1.f / 256.f) - m * m + 1e-5f);
        #pragma unroll
        for (int i = 0; i < 16; ++i) {
            const int cc = cg + i;
            shat[(long)(m0 + row) * DD + cc] =
                f2bf((Ct[row][cc] - m) * inv * ln2_g[cc] + ln2_b[cc]);
        }
    }
}

// ---------------------------------------------------------------------------
extern "C" void kernel_launch(void* const* d_in, const int* in_sizes, int n_in,
                              void* d_out, int out_size, void* d_ws, size_t ws_size,
                              hipStream_t stream)
{
    const float* x     = (const float*)d_in[0];
    const float* key_W = (const float*)d_in[1];
    const float* key_b = (const float*)d_in[2];
    const float* val_W = (const float*)d_in[3];
    const float* val_b = (const float*)d_in[4];
    const float* ln1_g = (const float*)d_in[5];
    const float* ln1_b = (const float*)d_in[6];
    const float* W1    = (const float*)d_in[7];
    const float* b1    = (const float*)d_in[8];
    const float* W2    = (const float*)d_in[9];
    const float* b2    = (const float*)d_in[10];
    const float* ln2_g = (const float*)d_in[11];
    const float* ln2_b = (const float*)d_in[12];
    const float* Wo    = (const float*)d_in[13];
    const float* bo    = (const float*)d_in[14];
    float* outp = (float*)d_out;

    float* ws = (float*)d_ws;
    float*  ph      = ws;                             // 262144 f32 (1 MB)
    float*  Mt      = ws + 262144;                    // 2097152 f32 (8 MB)
    ushort_t* VoddT = (ushort_t*)(Mt + 2097152);      // 524288 us (1 MB)
    ushort_t* rhat_b = VoddT + 524288;                // 1048576 us (2 MB)
    ushort_t* W1t   = rhat_b + 1048576;               // 131072 us
    ushort_t* W2t   = W1t + 131072;
    ushort_t* Wot   = W2t + 131072;
    ushort_t* valWt = Wot + 65536;
    // reuse Mt after retrieve:
    ushort_t* h_b    = (ushort_t*)Mt;                 // 4096x512 bf16 (4 MB)
    ushort_t* shat_b = (ushort_t*)(Mt + 1048576);     // 4096x256 bf16 (2 MB)

    prep_key_kernel<<<608, 256, 0, stream>>>(W1, W2, Wo, val_W, x, key_W, key_b,
                                             W1t, W2t, Wot, valWt, (float2*)ph);
    valbind_kernel<<<256, 256, 0, stream>>>(x, (const float2*)ph, valWt, val_b,
                                            VoddT, Mt);
    prefix_kernel<<<512, 256, 0, stream>>>(Mt);
    retrieve_kernel<<<256, 256, 0, stream>>>(ph, Mt, VoddT, ln1_g, ln1_b, rhat_b);
    mfma_gemm<256, 512, 0><<<256 * 8, 256, 0, stream>>>(rhat_b, W1t, b1, nullptr, h_b);
    gemm2ln_kernel<<<256, 256, 0, stream>>>(h_b, W2t, b2, ln2_g, ln2_b, shat_b);
    mfma_gemm<256, 256, 2><<<256 * 4, 256, 0, stream>>>(shat_b, Wot, bo, x, outp);
}

// Round 9
// 130.353 us; speedup vs baseline: 1.8454x; 1.0214x over previous
//
#include <hip/hip_runtime.h>
#include <math.h>

#define BB 2
#define LL 2048
#define DD 256
#define PP 32
#define NC 64
#define PI_F 3.14159265358979323846f

typedef __attribute__((ext_vector_type(8))) short bf16x8;
typedef __attribute__((ext_vector_type(4))) float f32x4;
typedef unsigned short ushort_t;
typedef unsigned int uint_t;

__device__ inline ushort_t f2bf(float x) {
    uint_t u = __float_as_uint(x);
    uint_t r = (u + 0x7fffu + ((u >> 16) & 1u)) >> 16;
    return (ushort_t)r;
}

// ---------------------------------------------------------------------------
// Kernel A: prep (weight transposes to bf16 [N][K]) + encode_key (MFMA).
// blocks 0-31: W1^T; 32-63: W2^T; 64-79: Wo^T; 80-95: val_W^T;
// blocks 96-351: phases (16 rows each, MFMA K-split across 4 waves).
// ---------------------------------------------------------------------------
__global__ __launch_bounds__(256) void prep_key_kernel(
    const float* __restrict__ W1, const float* __restrict__ W2,
    const float* __restrict__ Wo, const float* __restrict__ valW,
    const float* __restrict__ x, const float* __restrict__ key_W,
    const float* __restrict__ key_b,
    ushort_t* __restrict__ W1t, ushort_t* __restrict__ W2t,
    ushort_t* __restrict__ Wot, ushort_t* __restrict__ valWt,
    float2* __restrict__ ph)
{
    const int bid = blockIdx.x;
    const int t = threadIdx.x;
    if (bid < 96) {
        __shared__ float T[64][65];
        const float* W; ushort_t* Wt; int K, N, tile;
        if (bid < 32)      { W = W1;   Wt = W1t;   K = 256; N = 512; tile = bid; }
        else if (bid < 64) { W = W2;   Wt = W2t;   K = 512; N = 256; tile = bid - 32; }
        else if (bid < 80) { W = Wo;   Wt = Wot;   K = 256; N = 256; tile = bid - 64; }
        else               { W = valW; Wt = valWt; K = 256; N = 256; tile = bid - 80; }
        const int ntiles = N / 64;
        const int k0 = (tile / ntiles) * 64, n0 = (tile % ntiles) * 64;
        {
            const int rr = t >> 2, cb = (t & 3) * 16;
            #pragma unroll
            for (int i = 0; i < 16; i += 4) {
                const float4 v = *(const float4*)&W[(k0 + rr) * N + n0 + cb + i];
                T[rr][cb + i + 0] = v.x; T[rr][cb + i + 1] = v.y;
                T[rr][cb + i + 2] = v.z; T[rr][cb + i + 3] = v.w;
            }
        }
        __syncthreads();
        {
            const int n = t >> 2, kb = (t & 3) * 16;
            #pragma unroll
            for (int i = 0; i < 16; ++i)
                Wt[(n0 + n) * K + k0 + kb + i] = f2bf(T[kb + i][n]);
        }
    } else {
        // ---- phases via MFMA ----
        __shared__ ushort_t xt[16][264];     // x rows bf16 [l][k]
        __shared__ ushort_t kwT[32][264];    // key_W^T bf16 [p][k]
        __shared__ float rbuf[4][2][16][17]; // per-wave partials [wv][nf][l][mc]
        const int row0 = (bid - 96) * 16;
        {   // stage xt
            const int l = t >> 4, cb = (t & 15) * 16;
            const float* src = &x[(long)(row0 + l) * DD + cb];
            ushort_t tmp[16];
            #pragma unroll
            for (int i = 0; i < 4; ++i) {
                const float4 v = *(const float4*)&src[i * 4];
                tmp[i*4+0] = f2bf(v.x); tmp[i*4+1] = f2bf(v.y);
                tmp[i*4+2] = f2bf(v.z); tmp[i*4+3] = f2bf(v.w);
            }
            *(uint4*)&xt[l][cb]     = *(uint4*)&tmp[0];
            *(uint4*)&xt[l][cb + 8] = *(uint4*)&tmp[8];
        }
        {   // stage kwT (transpose key_W [256][32] -> [32][256] bf16)
            #pragma unroll
            for (int i = 0; i < 8; ++i) {
                const int idx4 = i * 256 + t;
                const int k = idx4 >> 3, pc = (idx4 & 7) * 4;
                const float4 v = *(const float4*)&key_W[k * 32 + pc];
                kwT[pc + 0][k] = f2bf(v.x);
                kwT[pc + 1][k] = f2bf(v.y);
                kwT[pc + 2][k] = f2bf(v.z);
                kwT[pc + 3][k] = f2bf(v.w);
            }
        }
        __syncthreads();
        const int wv = t >> 6, lane = t & 63;
        const int qd = lane >> 4, mc = lane & 15;
        f32x4 acc0 = {0.f,0.f,0.f,0.f}, acc1 = {0.f,0.f,0.f,0.f};
        #pragma unroll
        for (int ks = 0; ks < 2; ++ks) {
            const int ko = wv * 64 + ks * 32 + qd * 8;
            const bf16x8 a  = *(const bf16x8*)&xt[mc][ko];
            const bf16x8 b0 = *(const bf16x8*)&kwT[mc][ko];
            const bf16x8 b1 = *(const bf16x8*)&kwT[16 + mc][ko];
            acc0 = __builtin_amdgcn_mfma_f32_16x16x32_bf16(a, b0, acc0, 0, 0, 0);
            acc1 = __builtin_amdgcn_mfma_f32_16x16x32_bf16(a, b1, acc1, 0, 0, 0);
        }
        #pragma unroll
        for (int r = 0; r < 4; ++r) {
            rbuf[wv][0][qd * 4 + r][mc] = acc0[r];
            rbuf[wv][1][qd * 4 + r][mc] = acc1[r];
        }
        __syncthreads();
        #pragma unroll
        for (int rep = 0; rep < 2; ++rep) {
            const int idx = rep * 256 + t;
            const int p = idx & 31, l = idx >> 5;
            const int nf = p >> 4, mcol = p & 15;
            float a = key_b[p] + rbuf[0][nf][l][mcol] + rbuf[1][nf][l][mcol]
                    + rbuf[2][nf][l][mcol] + rbuf[3][nf][l][mcol];
            a = tanhf(a) * PI_F;
            float sn, cs;
            sincosf(a, &sn, &cs);
            ph[(long)(row0 + l) * PP + p] = make_float2(cs, sn);
        }
    }
}

// ---------------------------------------------------------------------------
// Kernel B: valbind. Block = (b, chunk c, d-quarter dq); grid 512.
// Phase 1 (MFMA): V_odd[j 16][dloc 64] = x[odd rows] @ valW + val_b
// Phase 2 (MFMA): M_c[q 64][dloc 64]; dump Mt [c][d][q] f32 + VoddT [c][d][j] bf16
// ---------------------------------------------------------------------------
__global__ __launch_bounds__(256) void valbind_kernel(
    const float* __restrict__ x, const float2* __restrict__ ph,
    const ushort_t* __restrict__ valWt, const float* __restrict__ val_b,
    ushort_t* __restrict__ VoddT, float* __restrict__ Mt)
{
    __shared__ ushort_t xsb[16][264];   // odd-row x tile, bf16 [j][k]
    __shared__ ushort_t VdT[64][40];    // values^T [dloc][j] bf16 (j-pad zeroed)
    __shared__ ushort_t phsT[64][40];   // shifted phasors [q][j] bf16
    __shared__ float    Ms[64][68];     // M^T [dloc][q] fp32

    const int tid = threadIdx.x;
    const int bid = blockIdx.x;
    const int b  = bid >> 8;
    const int c  = (bid >> 2) & 63;
    const int dq = bid & 3;
    const int base = b * LL;
    const int r0 = 32 * c;

    {   // stage xsb
        const int j = tid >> 4, cb = (tid & 15) * 16;
        const float* src = &x[(long)(base + r0 + 2 * j + 1) * DD + cb];
        ushort_t tmp[16];
        #pragma unroll
        for (int i = 0; i < 4; ++i) {
            const float4 v = *(const float4*)&src[i * 4];
            tmp[i*4+0] = f2bf(v.x); tmp[i*4+1] = f2bf(v.y);
            tmp[i*4+2] = f2bf(v.z); tmp[i*4+3] = f2bf(v.w);
        }
        *(uint4*)&xsb[j][cb]     = *(uint4*)&tmp[0];
        *(uint4*)&xsb[j][cb + 8] = *(uint4*)&tmp[8];
    }
    {   // stage phsT (transpose)
        const int j = tid >> 4, qb = (tid & 15) * 4;
        const float4 v = *(const float4*)((const float*)ph +
                              (long)(base + r0 + 2 * j) * 64 + qb);
        phsT[qb + 0][j] = f2bf(v.x);
        phsT[qb + 1][j] = f2bf(v.y);
        phsT[qb + 2][j] = f2bf(v.z);
        phsT[qb + 3][j] = f2bf(v.w);
    }
    for (int e = tid; e < 64 * 16; e += 256) {
        phsT[e >> 4][16 + (e & 15)] = 0;
        VdT[e >> 4][16 + (e & 15)] = 0;
    }
    __syncthreads();

    const int wv = tid >> 6, lane = tid & 63;
    const int qd = lane >> 4, mc = lane & 15;

    // ---- phase 1: values MFMA (one d-frag per wave) ----
    f32x4 va = {0.f,0.f,0.f,0.f};
    const int dloc = wv * 16 + mc;        // 0..63
    const int ng = dq * 64 + dloc;        // global val col
    const ushort_t* B0 = &valWt[(long)ng * 256];
    #pragma unroll
    for (int ks = 0; ks < 8; ++ks) {
        const bf16x8 a  = *(const bf16x8*)&xsb[mc][ks * 32 + qd * 8];
        const bf16x8 b0 = *(const bf16x8*)&B0[ks * 32 + qd * 8];
        va = __builtin_amdgcn_mfma_f32_16x16x32_bf16(a, b0, va, 0, 0, 0);
    }
    {
        const float bb = val_b[ng];
        #pragma unroll
        for (int r = 0; r < 4; ++r)
            VdT[dloc][qd * 4 + r] = f2bf(va[r] + bb);
    }
    __syncthreads();

    // ---- phase 2: bind MFMA (q-tile per wave, 4 d-frags, K=32 j-padded) ----
    const bf16x8 a2 = *(const bf16x8*)&phsT[wv * 16 + mc][qd * 8];
    f32x4 macc[4];
    #pragma unroll
    for (int nf = 0; nf < 4; ++nf) {
        f32x4 z = {0.f,0.f,0.f,0.f};
        const bf16x8 b2 = *(const bf16x8*)&VdT[nf * 16 + mc][qd * 8];
        macc[nf] = __builtin_amdgcn_mfma_f32_16x16x32_bf16(a2, b2, z, 0, 0, 0);
    }
    #pragma unroll
    for (int nf = 0; nf < 4; ++nf) {
        #pragma unroll
        for (int r = 0; r < 4; ++r)
            Ms[nf * 16 + mc][wv * 16 + qd * 4 + r] = macc[nf][r];
    }
    __syncthreads();

    // coalesced dumps
    {
        float* dst = &Mt[((long)(b * NC + c) * 256 + dq * 64) * 64];
        #pragma unroll
        for (int p = 0; p < 4; ++p) {
            const int idx4 = p * 256 + tid;
            const int dl = idx4 >> 4, q4 = (idx4 & 15) * 4;
            *(float4*)&dst[dl * 64 + q4] = *(const float4*)&Ms[dl][q4];
        }
    }
    if (tid < 64) {
        ushort_t* vd = &VoddT[((long)(b * NC + c) * 256 + dq * 64 + tid) * 16];
        *(uint4*)&vd[0] = *(const uint4*)&VdT[tid][0];
        *(uint4*)&vd[8] = *(const uint4*)&VdT[tid][8];
    }
}

// ---------------------------------------------------------------------------
// Kernel C: prefix. EXCLUSIVE scan of Mt over chunk c, 4-way segmented.
// ---------------------------------------------------------------------------
__global__ __launch_bounds__(256) void prefix_kernel(float* __restrict__ M)
{
    __shared__ float segsum[4][64];
    const int tid = threadIdx.x;
    const int b  = blockIdx.x >> 8;
    const int cg = blockIdx.x & 255;
    const int col = cg * 64 + (tid & 63);
    const int seg = tid >> 6;
    const long base = (long)b * NC * 16384 + col;

    float v[16], s = 0.f;
    #pragma unroll
    for (int i = 0; i < 16; ++i) {
        v[i] = M[base + (long)(seg * 16 + i) * 16384];
        s += v[i];
    }
    segsum[seg][tid & 63] = s;
    __syncthreads();
    float run = 0.f;
    #pragma unroll
    for (int sg = 0; sg < 3; ++sg)
        if (sg < seg) run += segsum[sg][tid & 63];
    #pragma unroll
    for (int i = 0; i < 16; ++i) {
        const long a = base + (long)(seg * 16 + i) * 16384;
        M[a] = run;
        run += v[i];
    }
}

// ---------------------------------------------------------------------------
// Kernel D: retrieve (MFMA) + LN1 -> rhat (bf16). Grid 256.
// ---------------------------------------------------------------------------
__global__ __launch_bounds__(256) void retrieve_kernel(
    const float* __restrict__ ph, const float* __restrict__ Mpre,
    const ushort_t* __restrict__ VoddT,
    const float* __restrict__ ln1_g, const float* __restrict__ ln1_b,
    ushort_t* __restrict__ rhat)
{
    __shared__ ushort_t Bs_m[256][72];  // Mpre^T bf16 [d][q]
    __shared__ ushort_t Bs_v[256][32];  // Vodd^T bf16 [d][j] (j-pad zeroed)
    __shared__ ushort_t As_ph[16][72];  // phi rows  [l][q]
    __shared__ ushort_t Bs_sh[16][72];  // shifted phi rows [j][q]
    __shared__ ushort_t As_p[16][32];   // masked scores [l][j] (pad zeroed)
    __shared__ float    ref[16][264];

    const int tid = threadIdx.x;
    const int b = blockIdx.x >> 7;
    const int c = (blockIdx.x >> 1) & 63;
    const int h = blockIdx.x & 1;
    const int l0g = 32 * c + 16 * h;
    const long rowbase = (long)b * LL + l0g;

    {   // stage Bs_m
        const float* src = &Mpre[(long)(b * NC + c) * 16384];
        #pragma unroll
        for (int p = 0; p < 16; ++p) {
            const int idx4 = p * 256 + tid;
            const int d = idx4 >> 4, q4 = (idx4 & 15) * 4;
            const float4 v = *(const float4*)&src[idx4 * 4];
            ushort_t tmp[4] = {f2bf(v.x), f2bf(v.y), f2bf(v.z), f2bf(v.w)};
            *(uint2*)&Bs_m[d][q4] = *(uint2*)tmp;
        }
    }
    {   // stage As_ph + Bs_sh
        const int r = tid >> 4, q4 = (tid & 15) * 4;
        const float4 v = *(const float4*)&ph[(rowbase + r) * 64 + q4];
        ushort_t t0[4] = {f2bf(v.x), f2bf(v.y), f2bf(v.z), f2bf(v.w)};
        *(uint2*)&As_ph[r][q4] = *(uint2*)t0;
        const float4 w = *(const float4*)&ph[((long)b * LL + 32 * c + 2 * r) * 64 + q4];
        ushort_t t1[4] = {f2bf(w.x), f2bf(w.y), f2bf(w.z), f2bf(w.w)};
        *(uint2*)&Bs_sh[r][q4] = *(uint2*)t1;
    }
    {   // stage Bs_v + zero pads
        const ushort_t* src = &VoddT[(long)(b * NC + c) * 4096];
        const int j0 = (tid & 1) * 8;
        *(uint4*)&Bs_v[tid >> 1][j0] = *(const uint4*)&src[tid * 8];
        *(uint4*)&Bs_v[(tid + 256) >> 1][j0] = *(const uint4*)&src[(tid + 256) * 8];
        *(uint4*)&Bs_v[tid][16] = make_uint4(0, 0, 0, 0);
        *(uint4*)&Bs_v[tid][24] = make_uint4(0, 0, 0, 0);
        As_p[tid >> 4][16 + (tid & 15)] = 0;
    }
    __syncthreads();

    const int wv = tid >> 6, lane = tid & 63;
    const int qd = lane >> 4, mc = lane & 15;

    // ---- S scores ----
    {
        f32x4 sacc = {0.f, 0.f, 0.f, 0.f};
        #pragma unroll
        for (int ks = 0; ks < 2; ++ks) {
            const bf16x8 a  = *(const bf16x8*)&As_ph[mc][ks * 32 + qd * 8];
            const bf16x8 bb = *(const bf16x8*)&Bs_sh[mc][ks * 32 + qd * 8];
            sacc = __builtin_amdgcn_mfma_f32_16x16x32_bf16(a, bb, sacc, 0, 0, 0);
        }
        if (wv == 0) {
            #pragma unroll
            for (int r = 0; r < 4; ++r) {
                const int l = qd * 4 + r;
                As_p[l][mc] = (2 * mc + 1 <= 16 * h + l) ? f2bf(sacc[r])
                                                         : (ushort_t)0;
            }
        }
    }

    // ---- main contraction ----
    f32x4 acc[4];
    #pragma unroll
    for (int i = 0; i < 4; ++i) acc[i] = (f32x4){0.f, 0.f, 0.f, 0.f};
    #pragma unroll
    for (int i = 0; i < 4; ++i) {
        const int d0 = wv * 64 + i * 16;
        #pragma unroll
        for (int ks = 0; ks < 2; ++ks) {
            const bf16x8 a  = *(const bf16x8*)&As_ph[mc][ks * 32 + qd * 8];
            const bf16x8 bb = *(const bf16x8*)&Bs_m[d0 + mc][ks * 32 + qd * 8];
            acc[i] = __builtin_amdgcn_mfma_f32_16x16x32_bf16(a, bb, acc[i], 0, 0, 0);
        }
    }
    __syncthreads();

    // ---- within-chunk correction ----
    {
        const bf16x8 a2 = *(const bf16x8*)&As_p[mc][qd * 8];
        #pragma unroll
        for (int i = 0; i < 4; ++i) {
            const int d0 = wv * 64 + i * 16;
            const bf16x8 b2 = *(const bf16x8*)&Bs_v[d0 + mc][qd * 8];
            acc[i] = __builtin_amdgcn_mfma_f32_16x16x32_bf16(a2, b2, acc[i], 0, 0, 0);
        }
    }

    // ---- scale -> ref ----
    #pragma unroll
    for (int r = 0; r < 4; ++r) {
        const int l = qd * 4 + r;
        int va = (l0g + l + 1) >> 1; if (va < 1) va = 1;
        const float sc = 0.17677669529663687f * rsqrtf((float)va);
        #pragma unroll
        for (int i = 0; i < 4; ++i)
            ref[l][wv * 64 + i * 16 + mc] = acc[i][r] * sc;
    }
    __syncthreads();

    // ---- LN1 -> rhat bf16 ----
    {
        const int row = tid >> 4, cg = (tid & 15) * 16;
        float s = 0.f, sq = 0.f;
        #pragma unroll
        for (int i = 0; i < 16; ++i) {
            const float v = ref[row][cg + i];
            s += v; sq += v * v;
        }
        s += __shfl_xor(s, 1, 16);  sq += __shfl_xor(sq, 1, 16);
        s += __shfl_xor(s, 2, 16);  sq += __shfl_xor(sq, 2, 16);
        s += __shfl_xor(s, 4, 16);  sq += __shfl_xor(sq, 4, 16);
        s += __shfl_xor(s, 8, 16);  sq += __shfl_xor(sq, 8, 16);
        const float m = s * (1.f / 256.f);
        const float inv = rsqrtf(sq * (1.f / 256.f) - m * m + 1e-5f);
        ushort_t o16[16];
        #pragma unroll
        for (int i = 0; i < 16; ++i) {
            const int cc = cg + i;
            o16[i] = f2bf((ref[row][cc] - m) * inv * ln1_g[cc] + ln1_b[cc]);
        }
        ushort_t* dst = &rhat[(rowbase + row) * DD + cg];
        *(uint4*)&dst[0] = *(uint4*)&o16[0];
        *(uint4*)&dst[8] = *(uint4*)&o16[8];
    }
}

// ---------------------------------------------------------------------------
// MFMA GEMM BM=32: C[4096][N] = A @ Bt^T + bias (+resid).
// MODE 0: gelu->bf16; MODE 2: bias+resid->f32.
// ---------------------------------------------------------------------------
template<int K, int N, int MODE>
__global__ __launch_bounds__(256) void mfma_gemm32(
    const ushort_t* __restrict__ A, const ushort_t* __restrict__ Bt,
    const float* __restrict__ bias, const float* __restrict__ resid,
    void* __restrict__ out)
{
    __shared__ ushort_t As[32][136];
    __shared__ ushort_t Bs[64][136];
    const int tid = threadIdx.x;
    const int mt = blockIdx.x & 127;
    const int nt = blockIdx.x >> 7;
    const int m0 = mt * 32, n0 = nt * 64;
    const int wv = tid >> 6, lane = tid & 63;
    const int qd = lane >> 4, mc = lane & 15;

    f32x4 acc0 = {0.f, 0.f, 0.f, 0.f};
    f32x4 acc1 = {0.f, 0.f, 0.f, 0.f};

    const int ar = tid >> 3, ak = (tid & 7) * 16;
    const int bn = tid >> 2, bk = (tid & 3) * 32;

    for (int k0 = 0; k0 < K; k0 += 128) {
        __syncthreads();
        {
            const ushort_t* sa = &A[(long)(m0 + ar) * K + k0 + ak];
            *(uint4*)&As[ar][ak]     = *(const uint4*)&sa[0];
            *(uint4*)&As[ar][ak + 8] = *(const uint4*)&sa[8];
        }
        {
            const ushort_t* src = &Bt[(long)(n0 + bn) * K + k0 + bk];
            *(uint4*)&Bs[bn][bk +  0] = *(const uint4*)&src[0];
            *(uint4*)&Bs[bn][bk +  8] = *(const uint4*)&src[8];
            *(uint4*)&Bs[bn][bk + 16] = *(const uint4*)&src[16];
            *(uint4*)&Bs[bn][bk + 24] = *(const uint4*)&src[24];
        }
        __syncthreads();
        #pragma unroll
        for (int ko = 0; ko < 128; ko += 32) {
            const bf16x8 a0 = *(const bf16x8*)&As[mc][ko + qd * 8];
            const bf16x8 a1 = *(const bf16x8*)&As[16 + mc][ko + qd * 8];
            const bf16x8 b  = *(const bf16x8*)&Bs[wv * 16 + mc][ko + qd * 8];
            acc0 = __builtin_amdgcn_mfma_f32_16x16x32_bf16(a0, b, acc0, 0, 0, 0);
            acc1 = __builtin_amdgcn_mfma_f32_16x16x32_bf16(a1, b, acc1, 0, 0, 0);
        }
    }

    const int nn = n0 + wv * 16 + mc;
    const float bb = bias[nn];
    #pragma unroll
    for (int r = 0; r < 4; ++r) {
        const long row0w = m0 + qd * 4 + r;
        const long row1w = row0w + 16;
        float v0 = acc0[r] + bb;
        float v1 = acc1[r] + bb;
        if (MODE == 0) {
            v0 = 0.5f * v0 * (1.f + erff(v0 * 0.70710678118654752f));
            v1 = 0.5f * v1 * (1.f + erff(v1 * 0.70710678118654752f));
            ((ushort_t*)out)[row0w * N + nn] = f2bf(v0);
            ((ushort_t*)out)[row1w * N + nn] = f2bf(v1);
        } else {
            ((float*)out)[row0w * N + nn] = v0 + resid[row0w * N + nn];
            ((float*)out)[row1w * N + nn] = v1 + resid[row1w * N + nn];
        }
    }
}

// ---------------------------------------------------------------------------
// Kernel F: gemm2 + LN2 fused. BM=16, BN=256, K=512; grid 256.
// ---------------------------------------------------------------------------
__global__ __launch_bounds__(256) void gemm2ln_kernel(
    const ushort_t* __restrict__ h, const ushort_t* __restrict__ W2t,
    const float* __restrict__ b2, const float* __restrict__ ln2_g,
    const float* __restrict__ ln2_b, ushort_t* __restrict__ shat)
{
    __shared__ ushort_t As[16][72];
    __shared__ ushort_t Bs[256][72];
    __shared__ float Ct[16][264];

    const int tid = threadIdx.x;
    const int m0 = blockIdx.x * 16;
    const int wv = tid >> 6, lane = tid & 63;
    const int qd = lane >> 4, mc = lane & 15;

    f32x4 acc[4];
    #pragma unroll
    for (int nf = 0; nf < 4; ++nf) acc[nf] = (f32x4){0.f,0.f,0.f,0.f};

    const int sr = tid >> 3, sk = (tid & 7) * 8;

    for (int k0 = 0; k0 < 512; k0 += 64) {
        __syncthreads();
        if (tid < 128)
            *(uint4*)&As[sr][sk] = *(const uint4*)&h[(long)(m0 + sr) * 512 + k0 + sk];
        #pragma unroll
        for (int rr = 0; rr < 8; ++rr) {
            const int n = rr * 32 + (tid >> 3);
            *(uint4*)&Bs[n][sk] = *(const uint4*)&W2t[(long)n * 512 + k0 + sk];
        }
        __syncthreads();
        #pragma unroll
        for (int ks = 0; ks < 2; ++ks) {
            const bf16x8 a = *(const bf16x8*)&As[mc][ks * 32 + qd * 8];
            #pragma unroll
            for (int nf = 0; nf < 4; ++nf) {
                const bf16x8 b = *(const bf16x8*)&Bs[wv * 64 + nf * 16 + mc][ks * 32 + qd * 8];
                acc[nf] = __builtin_amdgcn_mfma_f32_16x16x32_bf16(a, b, acc[nf], 0, 0, 0);
            }
        }
    }

    #pragma unroll
    for (int nf = 0; nf < 4; ++nf) {
        const int n = wv * 64 + nf * 16 + mc;
        const float bb = b2[n];
        #pragma unroll
        for (int r = 0; r < 4; ++r)
            Ct[qd * 4 + r][n] = acc[nf][r] + bb;
    }
    __syncthreads();

    {
        const int row = tid >> 4, cg = (tid & 15) * 16;
        float s = 0.f, sq = 0.f;
        #pragma unroll
        for (int i = 0; i < 16; ++i) {
            const float v = Ct[row][cg + i];
            s += v; sq += v * v;
        }
        s  += __shfl_xor(s, 1, 16);  sq += __shfl_xor(sq, 1, 16);
        s  += __shfl_xor(s, 2, 16);  sq += __shfl_xor(sq, 2, 16);
        s  += __shfl_xor(s, 4, 16);  sq += __shfl_xor(sq, 4, 16);
        s  += __shfl_xor(s, 8, 16);  sq += __shfl_xor(sq, 8, 16);
        const float m = s * (1.f / 256.f);
        const float inv = rsqrtf(sq * (1.f / 256.f) - m * m + 1e-5f);
        #pragma unroll
        for (int i = 0; i < 16; ++i) {
            const int cc = cg + i;
            shat[(long)(m0 + row) * DD + cc] =
                f2bf((Ct[row][cc] - m) * inv * ln2_g[cc] + ln2_b[cc]);
        }
    }
}

// ---------------------------------------------------------------------------
extern "C" void kernel_launch(void* const* d_in, const int* in_sizes, int n_in,
                              void* d_out, int out_size, void* d_ws, size_t ws_size,
                              hipStream_t stream)
{
    const float* x     = (const float*)d_in[0];
    const float* key_W = (const float*)d_in[1];
    const float* key_b = (const float*)d_in[2];
    const float* val_W = (const float*)d_in[3];
    const float* val_b = (const float*)d_in[4];
    const float* ln1_g = (const float*)d_in[5];
    const float* ln1_b = (const float*)d_in[6];
    const float* W1    = (const float*)d_in[7];
    const float* b1    = (const float*)d_in[8];
    const float* W2    = (const float*)d_in[9];
    const float* b2    = (const float*)d_in[10];
    const float* ln2_g = (const float*)d_in[11];
    const float* ln2_b = (const float*)d_in[12];
    const float* Wo    = (const float*)d_in[13];
    const float* bo    = (const float*)d_in[14];
    float* outp = (float*)d_out;

    float* ws = (float*)d_ws;
    float*  ph      = ws;                             // 262144 f32 (1 MB)
    float*  Mt      = ws + 262144;                    // 2097152 f32 (8 MB)
    ushort_t* VoddT = (ushort_t*)(Mt + 2097152);      // 524288 us (1 MB)
    ushort_t* rhat_b = VoddT + 524288;                // 1048576 us (2 MB)
    ushort_t* W1t   = rhat_b + 1048576;               // 131072 us
    ushort_t* W2t   = W1t + 131072;
    ushort_t* Wot   = W2t + 131072;
    ushort_t* valWt = Wot + 65536;
    // reuse Mt after retrieve:
    ushort_t* h_b    = (ushort_t*)Mt;                 // 4096x512 bf16 (4 MB)
    ushort_t* shat_b = (ushort_t*)(Mt + 1048576);     // 4096x256 bf16 (2 MB)

    prep_key_kernel<<<352, 256, 0, stream>>>(W1, W2, Wo, val_W, x, key_W, key_b,
                                             W1t, W2t, Wot, valWt, (float2*)ph);
    valbind_kernel<<<512, 256, 0, stream>>>(x, (const float2*)ph, valWt, val_b,
                                            VoddT, Mt);
    prefix_kernel<<<512, 256, 0, stream>>>(Mt);
    retrieve_kernel<<<256, 256, 0, stream>>>(ph, Mt, VoddT, ln1_g, ln1_b, rhat_b);
    mfma_gemm32<256, 512, 0><<<1024, 256, 0, stream>>>(rhat_b, W1t, b1, nullptr, h_b);
    gemm2ln_kernel<<<256, 256, 0, stream>>>(h_b, W2t, b2, ln2_g, ln2_b, shat_b);
    mfma_gemm32<256, 256, 2><<<512, 256, 0, stream>>>(shat_b, Wot, bo, x, outp);
}

// Round 10
// 124.144 us; speedup vs baseline: 1.9377x; 1.0500x over previous
//
#include <hip/hip_runtime.h>
#include <math.h>

#define BB 2
#define LL 2048
#define DD 256
#define PP 32
#define NC 64
#define PI_F 3.14159265358979323846f

typedef __attribute__((ext_vector_type(8))) short bf16x8;
typedef __attribute__((ext_vector_type(4))) float f32x4;
typedef unsigned short ushort_t;
typedef unsigned int uint_t;

__device__ inline ushort_t f2bf(float x) {
    uint_t u = __float_as_uint(x);
    uint_t r = (u + 0x7fffu + ((u >> 16) & 1u)) >> 16;
    return (ushort_t)r;
}

// ---------------------------------------------------------------------------
// Kernel A: prep (weight transposes to bf16 [N][K]) + encode_key (MFMA).
// blocks 0-31: W1^T; 32-63: W2^T; 64-79: Wo^T; 80-95: val_W^T;
// blocks 96-351: phases (16 rows each, MFMA K-split across 4 waves).
// ---------------------------------------------------------------------------
__global__ __launch_bounds__(256) void prep_key_kernel(
    const float* __restrict__ W1, const float* __restrict__ W2,
    const float* __restrict__ Wo, const float* __restrict__ valW,
    const float* __restrict__ x, const float* __restrict__ key_W,
    const float* __restrict__ key_b,
    ushort_t* __restrict__ W1t, ushort_t* __restrict__ W2t,
    ushort_t* __restrict__ Wot, ushort_t* __restrict__ valWt,
    float2* __restrict__ ph)
{
    const int bid = blockIdx.x;
    const int t = threadIdx.x;
    if (bid < 96) {
        __shared__ float T[64][65];
        const float* W; ushort_t* Wt; int K, N, tile;
        if (bid < 32)      { W = W1;   Wt = W1t;   K = 256; N = 512; tile = bid; }
        else if (bid < 64) { W = W2;   Wt = W2t;   K = 512; N = 256; tile = bid - 32; }
        else if (bid < 80) { W = Wo;   Wt = Wot;   K = 256; N = 256; tile = bid - 64; }
        else               { W = valW; Wt = valWt; K = 256; N = 256; tile = bid - 80; }
        const int ntiles = N / 64;
        const int k0 = (tile / ntiles) * 64, n0 = (tile % ntiles) * 64;
        {
            const int rr = t >> 2, cb = (t & 3) * 16;
            #pragma unroll
            for (int i = 0; i < 16; i += 4) {
                const float4 v = *(const float4*)&W[(k0 + rr) * N + n0 + cb + i];
                T[rr][cb + i + 0] = v.x; T[rr][cb + i + 1] = v.y;
                T[rr][cb + i + 2] = v.z; T[rr][cb + i + 3] = v.w;
            }
        }
        __syncthreads();
        {
            const int n = t >> 2, kb = (t & 3) * 16;
            #pragma unroll
            for (int i = 0; i < 16; ++i)
                Wt[(n0 + n) * K + k0 + kb + i] = f2bf(T[kb + i][n]);
        }
    } else {
        // ---- phases via MFMA ----
        __shared__ ushort_t xt[16][264];     // x rows bf16 [l][k]
        __shared__ ushort_t kwT[32][264];    // key_W^T bf16 [p][k]
        __shared__ float rbuf[4][2][16][17]; // per-wave partials
        const int row0 = (bid - 96) * 16;
        {
            const int l = t >> 4, cb = (t & 15) * 16;
            const float* src = &x[(long)(row0 + l) * DD + cb];
            ushort_t tmp[16];
            #pragma unroll
            for (int i = 0; i < 4; ++i) {
                const float4 v = *(const float4*)&src[i * 4];
                tmp[i*4+0] = f2bf(v.x); tmp[i*4+1] = f2bf(v.y);
                tmp[i*4+2] = f2bf(v.z); tmp[i*4+3] = f2bf(v.w);
            }
            *(uint4*)&xt[l][cb]     = *(uint4*)&tmp[0];
            *(uint4*)&xt[l][cb + 8] = *(uint4*)&tmp[8];
        }
        {
            #pragma unroll
            for (int i = 0; i < 8; ++i) {
                const int idx4 = i * 256 + t;
                const int k = idx4 >> 3, pc = (idx4 & 7) * 4;
                const float4 v = *(const float4*)&key_W[k * 32 + pc];
                kwT[pc + 0][k] = f2bf(v.x);
                kwT[pc + 1][k] = f2bf(v.y);
                kwT[pc + 2][k] = f2bf(v.z);
                kwT[pc + 3][k] = f2bf(v.w);
            }
        }
        __syncthreads();
        const int wv = t >> 6, lane = t & 63;
        const int qd = lane >> 4, mc = lane & 15;
        f32x4 acc0 = {0.f,0.f,0.f,0.f}, acc1 = {0.f,0.f,0.f,0.f};
        #pragma unroll
        for (int ks = 0; ks < 2; ++ks) {
            const int ko = wv * 64 + ks * 32 + qd * 8;
            const bf16x8 a  = *(const bf16x8*)&xt[mc][ko];
            const bf16x8 b0 = *(const bf16x8*)&kwT[mc][ko];
            const bf16x8 b1 = *(const bf16x8*)&kwT[16 + mc][ko];
            acc0 = __builtin_amdgcn_mfma_f32_16x16x32_bf16(a, b0, acc0, 0, 0, 0);
            acc1 = __builtin_amdgcn_mfma_f32_16x16x32_bf16(a, b1, acc1, 0, 0, 0);
        }
        #pragma unroll
        for (int r = 0; r < 4; ++r) {
            rbuf[wv][0][qd * 4 + r][mc] = acc0[r];
            rbuf[wv][1][qd * 4 + r][mc] = acc1[r];
        }
        __syncthreads();
        #pragma unroll
        for (int rep = 0; rep < 2; ++rep) {
            const int idx = rep * 256 + t;
            const int p = idx & 31, l = idx >> 5;
            const int nf = p >> 4, mcol = p & 15;
            float a = key_b[p] + rbuf[0][nf][l][mcol] + rbuf[1][nf][l][mcol]
                    + rbuf[2][nf][l][mcol] + rbuf[3][nf][l][mcol];
            a = tanhf(a) * PI_F;
            float sn, cs;
            sincosf(a, &sn, &cs);
            ph[(long)(row0 + l) * PP + p] = make_float2(cs, sn);
        }
    }
}

// ---------------------------------------------------------------------------
// Kernel B: valbind. Block = (b, chunk c, d-quarter dq); grid 512.
// ---------------------------------------------------------------------------
__global__ __launch_bounds__(256) void valbind_kernel(
    const float* __restrict__ x, const float2* __restrict__ ph,
    const ushort_t* __restrict__ valWt, const float* __restrict__ val_b,
    ushort_t* __restrict__ VoddT, float* __restrict__ Mt)
{
    __shared__ ushort_t xsb[16][264];
    __shared__ ushort_t VdT[64][40];
    __shared__ ushort_t phsT[64][40];
    __shared__ float    Ms[64][68];

    const int tid = threadIdx.x;
    const int bid = blockIdx.x;
    const int b  = bid >> 8;
    const int c  = (bid >> 2) & 63;
    const int dq = bid & 3;
    const int base = b * LL;
    const int r0 = 32 * c;

    {
        const int j = tid >> 4, cb = (tid & 15) * 16;
        const float* src = &x[(long)(base + r0 + 2 * j + 1) * DD + cb];
        ushort_t tmp[16];
        #pragma unroll
        for (int i = 0; i < 4; ++i) {
            const float4 v = *(const float4*)&src[i * 4];
            tmp[i*4+0] = f2bf(v.x); tmp[i*4+1] = f2bf(v.y);
            tmp[i*4+2] = f2bf(v.z); tmp[i*4+3] = f2bf(v.w);
        }
        *(uint4*)&xsb[j][cb]     = *(uint4*)&tmp[0];
        *(uint4*)&xsb[j][cb + 8] = *(uint4*)&tmp[8];
    }
    {
        const int j = tid >> 4, qb = (tid & 15) * 4;
        const float4 v = *(const float4*)((const float*)ph +
                              (long)(base + r0 + 2 * j) * 64 + qb);
        phsT[qb + 0][j] = f2bf(v.x);
        phsT[qb + 1][j] = f2bf(v.y);
        phsT[qb + 2][j] = f2bf(v.z);
        phsT[qb + 3][j] = f2bf(v.w);
    }
    for (int e = tid; e < 64 * 16; e += 256) {
        phsT[e >> 4][16 + (e & 15)] = 0;
        VdT[e >> 4][16 + (e & 15)] = 0;
    }
    __syncthreads();

    const int wv = tid >> 6, lane = tid & 63;
    const int qd = lane >> 4, mc = lane & 15;

    f32x4 va = {0.f,0.f,0.f,0.f};
    const int dloc = wv * 16 + mc;
    const int ng = dq * 64 + dloc;
    const ushort_t* B0 = &valWt[(long)ng * 256];
    #pragma unroll
    for (int ks = 0; ks < 8; ++ks) {
        const bf16x8 a  = *(const bf16x8*)&xsb[mc][ks * 32 + qd * 8];
        const bf16x8 b0 = *(const bf16x8*)&B0[ks * 32 + qd * 8];
        va = __builtin_amdgcn_mfma_f32_16x16x32_bf16(a, b0, va, 0, 0, 0);
    }
    {
        const float bb = val_b[ng];
        #pragma unroll
        for (int r = 0; r < 4; ++r)
            VdT[dloc][qd * 4 + r] = f2bf(va[r] + bb);
    }
    __syncthreads();

    const bf16x8 a2 = *(const bf16x8*)&phsT[wv * 16 + mc][qd * 8];
    f32x4 macc[4];
    #pragma unroll
    for (int nf = 0; nf < 4; ++nf) {
        f32x4 z = {0.f,0.f,0.f,0.f};
        const bf16x8 b2 = *(const bf16x8*)&VdT[nf * 16 + mc][qd * 8];
        macc[nf] = __builtin_amdgcn_mfma_f32_16x16x32_bf16(a2, b2, z, 0, 0, 0);
    }
    #pragma unroll
    for (int nf = 0; nf < 4; ++nf) {
        #pragma unroll
        for (int r = 0; r < 4; ++r)
            Ms[nf * 16 + mc][wv * 16 + qd * 4 + r] = macc[nf][r];
    }
    __syncthreads();

    {
        float* dst = &Mt[((long)(b * NC + c) * 256 + dq * 64) * 64];
        #pragma unroll
        for (int p = 0; p < 4; ++p) {
            const int idx4 = p * 256 + tid;
            const int dl = idx4 >> 4, q4 = (idx4 & 15) * 4;
            *(float4*)&dst[dl * 64 + q4] = *(const float4*)&Ms[dl][q4];
        }
    }
    if (tid < 64) {
        ushort_t* vd = &VoddT[((long)(b * NC + c) * 256 + dq * 64 + tid) * 16];
        *(uint4*)&vd[0] = *(const uint4*)&VdT[tid][0];
        *(uint4*)&vd[8] = *(const uint4*)&VdT[tid][8];
    }
}

// ---------------------------------------------------------------------------
// Kernel C: prefix. EXCLUSIVE scan of Mt over chunk c -> bf16 Mpre_b.
// ---------------------------------------------------------------------------
__global__ __launch_bounds__(256) void prefix_kernel(
    const float* __restrict__ M, ushort_t* __restrict__ Mpre_b)
{
    __shared__ float segsum[4][64];
    const int tid = threadIdx.x;
    const int b  = blockIdx.x >> 8;
    const int cg = blockIdx.x & 255;
    const int col = cg * 64 + (tid & 63);
    const int seg = tid >> 6;
    const long base = (long)b * NC * 16384 + col;

    float v[16], s = 0.f;
    #pragma unroll
    for (int i = 0; i < 16; ++i) {
        v[i] = M[base + (long)(seg * 16 + i) * 16384];
        s += v[i];
    }
    segsum[seg][tid & 63] = s;
    __syncthreads();
    float run = 0.f;
    #pragma unroll
    for (int sg = 0; sg < 3; ++sg)
        if (sg < seg) run += segsum[sg][tid & 63];
    #pragma unroll
    for (int i = 0; i < 16; ++i) {
        const long a = base + (long)(seg * 16 + i) * 16384;
        Mpre_b[a] = f2bf(run);
        run += v[i];
    }
}

// ---------------------------------------------------------------------------
// Kernel D: retrieve (MFMA) + LN1 -> rhat (bf16). Grid 256.
// ---------------------------------------------------------------------------
__global__ __launch_bounds__(256) void retrieve_kernel(
    const float* __restrict__ ph, const ushort_t* __restrict__ Mpre_b,
    const ushort_t* __restrict__ VoddT,
    const float* __restrict__ ln1_g, const float* __restrict__ ln1_b,
    ushort_t* __restrict__ rhat)
{
    __shared__ ushort_t Bs_m[256][72];  // Mpre^T bf16 [d][q]
    __shared__ ushort_t Bs_v[256][32];  // Vodd^T bf16 [d][j] (j-pad zeroed)
    __shared__ ushort_t As_ph[16][72];  // phi rows  [l][q]
    __shared__ ushort_t Bs_sh[16][72];  // shifted phi rows [j][q]
    __shared__ ushort_t As_p[16][32];   // masked scores [l][j] (pad zeroed)
    __shared__ float    ref[16][264];

    const int tid = threadIdx.x;
    const int b = blockIdx.x >> 7;
    const int c = (blockIdx.x >> 1) & 63;
    const int h = blockIdx.x & 1;
    const int l0g = 32 * c + 16 * h;
    const long rowbase = (long)b * LL + l0g;

    {   // stage Bs_m straight bf16 copy (8 uint4 per thread)
        const ushort_t* src = &Mpre_b[(long)(b * NC + c) * 16384];
        #pragma unroll
        for (int p = 0; p < 8; ++p) {
            const int idx8 = p * 256 + tid;
            const int d = idx8 >> 3, q8 = (idx8 & 7) * 8;
            *(uint4*)&Bs_m[d][q8] = *(const uint4*)&src[idx8 * 8];
        }
    }
    {   // stage As_ph + Bs_sh
        const int r = tid >> 4, q4 = (tid & 15) * 4;
        const float4 v = *(const float4*)&ph[(rowbase + r) * 64 + q4];
        ushort_t t0[4] = {f2bf(v.x), f2bf(v.y), f2bf(v.z), f2bf(v.w)};
        *(uint2*)&As_ph[r][q4] = *(uint2*)t0;
        const float4 w = *(const float4*)&ph[((long)b * LL + 32 * c + 2 * r) * 64 + q4];
        ushort_t t1[4] = {f2bf(w.x), f2bf(w.y), f2bf(w.z), f2bf(w.w)};
        *(uint2*)&Bs_sh[r][q4] = *(uint2*)t1;
    }
    {   // stage Bs_v + zero pads
        const ushort_t* src = &VoddT[(long)(b * NC + c) * 4096];
        const int j0 = (tid & 1) * 8;
        *(uint4*)&Bs_v[tid >> 1][j0] = *(const uint4*)&src[tid * 8];
        *(uint4*)&Bs_v[(tid + 256) >> 1][j0] = *(const uint4*)&src[(tid + 256) * 8];
        *(uint4*)&Bs_v[tid][16] = make_uint4(0, 0, 0, 0);
        *(uint4*)&Bs_v[tid][24] = make_uint4(0, 0, 0, 0);
        As_p[tid >> 4][16 + (tid & 15)] = 0;
    }
    __syncthreads();

    const int wv = tid >> 6, lane = tid & 63;
    const int qd = lane >> 4, mc = lane & 15;

    // ---- S scores ----
    {
        f32x4 sacc = {0.f, 0.f, 0.f, 0.f};
        #pragma unroll
        for (int ks = 0; ks < 2; ++ks) {
            const bf16x8 a  = *(const bf16x8*)&As_ph[mc][ks * 32 + qd * 8];
            const bf16x8 bb = *(const bf16x8*)&Bs_sh[mc][ks * 32 + qd * 8];
            sacc = __builtin_amdgcn_mfma_f32_16x16x32_bf16(a, bb, sacc, 0, 0, 0);
        }
        if (wv == 0) {
            #pragma unroll
            for (int r = 0; r < 4; ++r) {
                const int l = qd * 4 + r;
                As_p[l][mc] = (2 * mc + 1 <= 16 * h + l) ? f2bf(sacc[r])
                                                         : (ushort_t)0;
            }
        }
    }

    // ---- main contraction ----
    f32x4 acc[4];
    #pragma unroll
    for (int i = 0; i < 4; ++i) acc[i] = (f32x4){0.f, 0.f, 0.f, 0.f};
    #pragma unroll
    for (int i = 0; i < 4; ++i) {
        const int d0 = wv * 64 + i * 16;
        #pragma unroll
        for (int ks = 0; ks < 2; ++ks) {
            const bf16x8 a  = *(const bf16x8*)&As_ph[mc][ks * 32 + qd * 8];
            const bf16x8 bb = *(const bf16x8*)&Bs_m[d0 + mc][ks * 32 + qd * 8];
            acc[i] = __builtin_amdgcn_mfma_f32_16x16x32_bf16(a, bb, acc[i], 0, 0, 0);
        }
    }
    __syncthreads();

    // ---- within-chunk correction ----
    {
        const bf16x8 a2 = *(const bf16x8*)&As_p[mc][qd * 8];
        #pragma unroll
        for (int i = 0; i < 4; ++i) {
            const int d0 = wv * 64 + i * 16;
            const bf16x8 b2 = *(const bf16x8*)&Bs_v[d0 + mc][qd * 8];
            acc[i] = __builtin_amdgcn_mfma_f32_16x16x32_bf16(a2, b2, acc[i], 0, 0, 0);
        }
    }

    // ---- scale -> ref ----
    #pragma unroll
    for (int r = 0; r < 4; ++r) {
        const int l = qd * 4 + r;
        int va = (l0g + l + 1) >> 1; if (va < 1) va = 1;
        const float sc = 0.17677669529663687f * rsqrtf((float)va);
        #pragma unroll
        for (int i = 0; i < 4; ++i)
            ref[l][wv * 64 + i * 16 + mc] = acc[i][r] * sc;
    }
    __syncthreads();

    // ---- LN1 -> rhat bf16 ----
    {
        const int row = tid >> 4, cg = (tid & 15) * 16;
        float s = 0.f, sq = 0.f;
        #pragma unroll
        for (int i = 0; i < 16; ++i) {
            const float v = ref[row][cg + i];
            s += v; sq += v * v;
        }
        s += __shfl_xor(s, 1, 16);  sq += __shfl_xor(sq, 1, 16);
        s += __shfl_xor(s, 2, 16);  sq += __shfl_xor(sq, 2, 16);
        s += __shfl_xor(s, 4, 16);  sq += __shfl_xor(sq, 4, 16);
        s += __shfl_xor(s, 8, 16);  sq += __shfl_xor(sq, 8, 16);
        const float m = s * (1.f / 256.f);
        const float inv = rsqrtf(sq * (1.f / 256.f) - m * m + 1e-5f);
        ushort_t o16[16];
        #pragma unroll
        for (int i = 0; i < 16; ++i) {
            const int cc = cg + i;
            o16[i] = f2bf((ref[row][cc] - m) * inv * ln1_g[cc] + ln1_b[cc]);
        }
        ushort_t* dst = &rhat[(rowbase + row) * DD + cg];
        *(uint4*)&dst[0] = *(uint4*)&o16[0];
        *(uint4*)&dst[8] = *(uint4*)&o16[8];
    }
}

// ---------------------------------------------------------------------------
// gemm1: h = gelu(rhat @ W1^T + b1). BM=32, grid 1024.
// ---------------------------------------------------------------------------
__global__ __launch_bounds__(256) void gemm1_kernel(
    const ushort_t* __restrict__ A, const ushort_t* __restrict__ Bt,
    const float* __restrict__ bias, ushort_t* __restrict__ out)
{
    __shared__ ushort_t As[32][136];
    __shared__ ushort_t Bs[64][136];
    const int tid = threadIdx.x;
    const int mt = blockIdx.x & 127;
    const int nt = blockIdx.x >> 7;
    const int m0 = mt * 32, n0 = nt * 64;
    const int wv = tid >> 6, lane = tid & 63;
    const int qd = lane >> 4, mc = lane & 15;

    f32x4 acc0 = {0.f, 0.f, 0.f, 0.f};
    f32x4 acc1 = {0.f, 0.f, 0.f, 0.f};

    const int ar = tid >> 3, ak = (tid & 7) * 16;
    const int bn = tid >> 2, bk = (tid & 3) * 32;

    for (int k0 = 0; k0 < 256; k0 += 128) {
        __syncthreads();
        {
            const ushort_t* sa = &A[(long)(m0 + ar) * 256 + k0 + ak];
            *(uint4*)&As[ar][ak]     = *(const uint4*)&sa[0];
            *(uint4*)&As[ar][ak + 8] = *(const uint4*)&sa[8];
        }
        {
            const ushort_t* src = &Bt[(long)(n0 + bn) * 256 + k0 + bk];
            *(uint4*)&Bs[bn][bk +  0] = *(const uint4*)&src[0];
            *(uint4*)&Bs[bn][bk +  8] = *(const uint4*)&src[8];
            *(uint4*)&Bs[bn][bk + 16] = *(const uint4*)&src[16];
            *(uint4*)&Bs[bn][bk + 24] = *(const uint4*)&src[24];
        }
        __syncthreads();
        #pragma unroll
        for (int ko = 0; ko < 128; ko += 32) {
            const bf16x8 a0 = *(const bf16x8*)&As[mc][ko + qd * 8];
            const bf16x8 a1 = *(const bf16x8*)&As[16 + mc][ko + qd * 8];
            const bf16x8 b  = *(const bf16x8*)&Bs[wv * 16 + mc][ko + qd * 8];
            acc0 = __builtin_amdgcn_mfma_f32_16x16x32_bf16(a0, b, acc0, 0, 0, 0);
            acc1 = __builtin_amdgcn_mfma_f32_16x16x32_bf16(a1, b, acc1, 0, 0, 0);
        }
    }

    const int nn = n0 + wv * 16 + mc;
    const float bb = bias[nn];
    #pragma unroll
    for (int r = 0; r < 4; ++r) {
        const long row0w = m0 + qd * 4 + r;
        float v0 = acc0[r] + bb;
        float v1 = acc1[r] + bb;
        v0 = 0.5f * v0 * (1.f + erff(v0 * 0.70710678118654752f));
        v1 = 0.5f * v1 * (1.f + erff(v1 * 0.70710678118654752f));
        out[row0w * 512 + nn] = f2bf(v0);
        out[(row0w + 16) * 512 + nn] = f2bf(v1);
    }
}

// ---------------------------------------------------------------------------
// Kernel F: gemm2 + LN2 + gemm3 fused. BM=16, grid 256.
// Phase A: refined = h @ W2^T + b2 (K=512, N=256) -> Ct; LN2 -> shT (LDS bf16)
// Phase B: out = x + shT @ Wo^T + bo (K=256, N=256)
// ---------------------------------------------------------------------------
__global__ __launch_bounds__(256) void gemm23_kernel(
    const ushort_t* __restrict__ h, const ushort_t* __restrict__ W2t,
    const float* __restrict__ b2, const float* __restrict__ ln2_g,
    const float* __restrict__ ln2_b, const ushort_t* __restrict__ Wot,
    const float* __restrict__ bo, const float* __restrict__ x,
    float* __restrict__ out)
{
    __shared__ ushort_t As[16][72];
    __shared__ ushort_t Bs[256][72];
    __shared__ float Ct[16][264];
    __shared__ ushort_t shT[16][264];

    const int tid = threadIdx.x;
    const int m0 = blockIdx.x * 16;
    const int wv = tid >> 6, lane = tid & 63;
    const int qd = lane >> 4, mc = lane & 15;

    f32x4 acc[4];
    #pragma unroll
    for (int nf = 0; nf < 4; ++nf) acc[nf] = (f32x4){0.f,0.f,0.f,0.f};

    const int sr = tid >> 3, sk = (tid & 7) * 8;

    // ---- Phase A: h @ W2^T ----
    for (int k0 = 0; k0 < 512; k0 += 64) {
        __syncthreads();
        if (tid < 128)
            *(uint4*)&As[sr][sk] = *(const uint4*)&h[(long)(m0 + sr) * 512 + k0 + sk];
        #pragma unroll
        for (int rr = 0; rr < 8; ++rr) {
            const int n = rr * 32 + (tid >> 3);
            *(uint4*)&Bs[n][sk] = *(const uint4*)&W2t[(long)n * 512 + k0 + sk];
        }
        __syncthreads();
        #pragma unroll
        for (int ks = 0; ks < 2; ++ks) {
            const bf16x8 a = *(const bf16x8*)&As[mc][ks * 32 + qd * 8];
            #pragma unroll
            for (int nf = 0; nf < 4; ++nf) {
                const bf16x8 b = *(const bf16x8*)&Bs[wv * 64 + nf * 16 + mc][ks * 32 + qd * 8];
                acc[nf] = __builtin_amdgcn_mfma_f32_16x16x32_bf16(a, b, acc[nf], 0, 0, 0);
            }
        }
    }

    #pragma unroll
    for (int nf = 0; nf < 4; ++nf) {
        const int n = wv * 64 + nf * 16 + mc;
        const float bb = b2[n];
        #pragma unroll
        for (int r = 0; r < 4; ++r)
            Ct[qd * 4 + r][n] = acc[nf][r] + bb;
    }
    __syncthreads();

    // ---- LN2 -> shT (bf16, LDS) ----
    {
        const int row = tid >> 4, cg = (tid & 15) * 16;
        float s = 0.f, sq = 0.f;
        #pragma unroll
        for (int i = 0; i < 16; ++i) {
            const float v = Ct[row][cg + i];
            s += v; sq += v * v;
        }
        s  += __shfl_xor(s, 1, 16);  sq += __shfl_xor(sq, 1, 16);
        s  += __shfl_xor(s, 2, 16);  sq += __shfl_xor(sq, 2, 16);
        s  += __shfl_xor(s, 4, 16);  sq += __shfl_xor(sq, 4, 16);
        s  += __shfl_xor(s, 8, 16);  sq += __shfl_xor(sq, 8, 16);
        const float m = s * (1.f / 256.f);
        const float inv = rsqrtf(sq * (1.f / 256.f) - m * m + 1e-5f);
        #pragma unroll
        for (int i = 0; i < 16; ++i) {
            const int cc = cg + i;
            shT[row][cc] = f2bf((Ct[row][cc] - m) * inv * ln2_g[cc] + ln2_b[cc]);
        }
    }

    // ---- Phase B: shT @ Wo^T + bo + x ----
    f32x4 acc2[4];
    #pragma unroll
    for (int nf = 0; nf < 4; ++nf) acc2[nf] = (f32x4){0.f,0.f,0.f,0.f};

    for (int k0 = 0; k0 < 256; k0 += 64) {
        __syncthreads();
        #pragma unroll
        for (int rr = 0; rr < 8; ++rr) {
            const int n = rr * 32 + (tid >> 3);
            *(uint4*)&Bs[n][sk] = *(const uint4*)&Wot[(long)n * 256 + k0 + sk];
        }
        __syncthreads();
        #pragma unroll
        for (int ks = 0; ks < 2; ++ks) {
            const bf16x8 a = *(const bf16x8*)&shT[mc][k0 + ks * 32 + qd * 8];
            #pragma unroll
            for (int nf = 0; nf < 4; ++nf) {
                const bf16x8 b = *(const bf16x8*)&Bs[wv * 64 + nf * 16 + mc][ks * 32 + qd * 8];
                acc2[nf] = __builtin_amdgcn_mfma_f32_16x16x32_bf16(a, b, acc2[nf], 0, 0, 0);
            }
        }
    }

    #pragma unroll
    for (int nf = 0; nf < 4; ++nf) {
        const int n = wv * 64 + nf * 16 + mc;
        const float bb = bo[n];
        #pragma unroll
        for (int r = 0; r < 4; ++r) {
            const long row = m0 + qd * 4 + r;
            out[row * DD + n] = acc2[nf][r] + bb + x[row * DD + n];
        }
    }
}

// ---------------------------------------------------------------------------
extern "C" void kernel_launch(void* const* d_in, const int* in_sizes, int n_in,
                              void* d_out, int out_size, void* d_ws, size_t ws_size,
                              hipStream_t stream)
{
    const float* x     = (const float*)d_in[0];
    const float* key_W = (const float*)d_in[1];
    const float* key_b = (const float*)d_in[2];
    const float* val_W = (const float*)d_in[3];
    const float* val_b = (const float*)d_in[4];
    const float* ln1_g = (const float*)d_in[5];
    const float* ln1_b = (const float*)d_in[6];
    const float* W1    = (const float*)d_in[7];
    const float* b1    = (const float*)d_in[8];
    const float* W2    = (const float*)d_in[9];
    const float* b2    = (const float*)d_in[10];
    const float* ln2_g = (const float*)d_in[11];
    const float* ln2_b = (const float*)d_in[12];
    const float* Wo    = (const float*)d_in[13];
    const float* bo    = (const float*)d_in[14];
    float* outp = (float*)d_out;

    float* ws = (float*)d_ws;
    float*  ph      = ws;                             // 262144 f32 (1 MB)
    float*  Mt      = ws + 262144;                    // 2097152 f32 (8 MB)
    ushort_t* Mpre_b = (ushort_t*)(Mt + 2097152);     // 2097152 us (4 MB)
    ushort_t* VoddT  = Mpre_b + 2097152;              // 524288 us (1 MB)
    ushort_t* rhat_b = VoddT + 524288;                // 1048576 us (2 MB)
    ushort_t* W1t   = rhat_b + 1048576;               // 131072 us
    ushort_t* W2t   = W1t + 131072;
    ushort_t* Wot   = W2t + 131072;
    ushort_t* valWt = Wot + 65536;
    // reuse Mt after prefix:
    ushort_t* h_b    = (ushort_t*)Mt;                 // 4096x512 bf16 (4 MB)

    prep_key_kernel<<<352, 256, 0, stream>>>(W1, W2, Wo, val_W, x, key_W, key_b,
                                             W1t, W2t, Wot, valWt, (float2*)ph);
    valbind_kernel<<<512, 256, 0, stream>>>(x, (const float2*)ph, valWt, val_b,
                                            VoddT, Mt);
    prefix_kernel<<<512, 256, 0, stream>>>(Mt, Mpre_b);
    retrieve_kernel<<<256, 256, 0, stream>>>(ph, Mpre_b, VoddT, ln1_g, ln1_b, rhat_b);
    gemm1_kernel<<<1024, 256, 0, stream>>>(rhat_b, W1t, b1, h_b);
    gemm23_kernel<<<256, 256, 0, stream>>>(h_b, W2t, b2, ln2_g, ln2_b,
                                           Wot, bo, x, outp);
}